// Round 9
// baseline (394.934 us; speedup 1.0000x reference)
//
#include <hip/hip_runtime.h>
#include <hip/hip_bf16.h>
#include <stdint.h>

typedef __attribute__((ext_vector_type(8))) short short8;
typedef __attribute__((ext_vector_type(4))) short short4v;
typedef __attribute__((ext_vector_type(4))) float f32x4;

static __device__ __forceinline__ ushort f2bf(float f) {
    uint32_t u = __builtin_bit_cast(uint32_t, f);
    uint32_t r = (u + 0x7FFFu + ((u >> 16) & 1u)) >> 16;
    return (ushort)r;
}

static __device__ __forceinline__ void async_copy16(const void* g, void* l) {
    __builtin_amdgcn_global_load_lds(
        (const __attribute__((address_space(1))) uint32_t*)g,
        (__attribute__((address_space(3))) uint32_t*)l, 16, 0, 0);
}

// ds_read_b64_tr_b16: tile = addr & ~127 ([4][16] bf16 row-major subtile),
// col = (addr>>3)&15; returns 4 bf16 at tile + col*2 + {0,32,64,96}.
static __device__ __forceinline__ short4v tr16(const ushort* p) {
    short4v d;
    const __attribute__((address_space(3))) ushort* p3 =
        (const __attribute__((address_space(3))) ushort*)p;
    asm volatile("ds_read_b64_tr_b16 %0, %1" : "=v"(d) : "v"(p3));
    return d;
}

// ---------------- cast fp32 -> bf16 ----------------
__global__ __launch_bounds__(256) void cast_kernel(const float* __restrict__ in,
                                                   ushort* __restrict__ out, int n4) {
    int i = blockIdx.x * 256 + threadIdx.x;
    if (i >= n4) return;
    float4 v = reinterpret_cast<const float4*>(in)[i];
    ushort4 o;
    o.x = f2bf(v.x); o.y = f2bf(v.y); o.z = f2bf(v.z); o.w = f2bf(v.w);
    reinterpret_cast<ushort4*>(out)[i] = o;
}

// ---------------- GEMM: C[M][N] = A[M][K] * B[N][K]^T (bf16 in, fp32 acc) ----------------
static __device__ __forceinline__ void store_val(float* C, size_t idx, float v) { C[idx] = v; }
static __device__ __forceinline__ void store_val(ushort* C, size_t idx, float v) { C[idx] = f2bf(v); }

template <typename OutT>
__global__ __launch_bounds__(256) void gemm_bt_kernel(const ushort* __restrict__ A,
                                                      const ushort* __restrict__ B,
                                                      OutT* __restrict__ C,
                                                      int M, int N, int K) {
    __shared__ __align__(16) ushort As[128 * 32];
    __shared__ __align__(16) ushort Bs[128 * 32];
    const int tid = threadIdx.x;
    const int w = tid >> 6, lane = tid & 63;
    const int fr = lane & 15, fq = lane >> 4;
    const int wr = w >> 1, wc = w & 1;
    const int bpn = N >> 7;
    const int which = blockIdx.x / bpn;
    const int row0 = blockIdx.y * 128;
    const int gcol0 = blockIdx.x * 128;
    const int col0 = gcol0 - which * N;
    OutT* Cw = C + (size_t)which * M * N;

    const int srow = tid >> 2;
    const int scol = (tid & 3) * 8;
    const ushort* ga0 = A + (size_t)(row0 + srow) * K + scol;
    const ushort* ga1 = A + (size_t)(row0 + 64 + srow) * K + scol;
    const ushort* gb0 = B + (size_t)(gcol0 + srow) * K + scol;
    const ushort* gb1 = B + (size_t)(gcol0 + 64 + srow) * K + scol;
    ushort* la0 = &As[(w * 64) * 8];
    ushort* la1 = &As[(256 + w * 64) * 8];
    ushort* lb0 = &Bs[(w * 64) * 8];
    ushort* lb1 = &Bs[(256 + w * 64) * 8];

    f32x4 acc[4][4];
#pragma unroll
    for (int m = 0; m < 4; ++m)
#pragma unroll
        for (int n = 0; n < 4; ++n) acc[m][n] = f32x4{0.f, 0.f, 0.f, 0.f};

    for (int kt = 0; kt < K; kt += 32) {
        __syncthreads();
        async_copy16(ga0 + kt, la0);
        async_copy16(ga1 + kt, la1);
        async_copy16(gb0 + kt, lb0);
        async_copy16(gb1 + kt, lb1);
        __syncthreads();
        short8 af[4], bfr[4];
#pragma unroll
        for (int m = 0; m < 4; ++m)
            af[m] = *(const short8*)&As[(wr * 64 + m * 16 + fr) * 32 + fq * 8];
#pragma unroll
        for (int n = 0; n < 4; ++n)
            bfr[n] = *(const short8*)&Bs[(wc * 64 + n * 16 + fr) * 32 + fq * 8];
#pragma unroll
        for (int m = 0; m < 4; ++m)
#pragma unroll
            for (int n = 0; n < 4; ++n)
                acc[m][n] = __builtin_amdgcn_mfma_f32_16x16x32_bf16(af[m], bfr[n], acc[m][n], 0, 0, 0);
    }

#pragma unroll
    for (int m = 0; m < 4; ++m) {
        const int grow = row0 + wr * 64 + m * 16 + fq * 4;
#pragma unroll
        for (int n = 0; n < 4; ++n) {
            const int gcol = col0 + wc * 64 + n * 16 + fr;
#pragma unroll
            for (int r = 0; r < 4; ++r)
                store_val(Cw, (size_t)(grow + r) * N + gcol, acc[m][n][r]);
        }
    }
}

// ---------------- flash attention fwd ----------------
// QBLK=64 (4 waves x 16 q-rows), KBLK=64. LDS exactly 40960 B (4 blocks/CU).
// Rotating single-buffer pipeline: K(t+1) staged after Ks-free barrier,
// V(t+1) staged after Vs-free barrier; counted vmcnt waits (never drain
// mid-loop except the V-wait which has nothing else outstanding).
__global__ __launch_bounds__(256) void attn_kernel(const ushort* __restrict__ Q,
                                                   const ushort* __restrict__ K,
                                                   const ushort* __restrict__ V,
                                                   ushort* __restrict__ O,
                                                   int S, int HID, float scale) {
    __shared__ __align__(16) ushort Ks[64 * 128];   // swz: byte ^= ((row&7)<<4)
    __shared__ __align__(16) ushort Vs[64 * 128];   // [kv/4][dh/16][4][16] subtiled
    __shared__ __align__(16) ushort Ps[4][16 * 64]; // packed; swz: byte ^= ((q&7)<<4)

    const int tid = threadIdx.x, w = tid >> 6, lane = tid & 63;
    const int fr = lane & 15, fq = lane >> 4;
    const int qt = blockIdx.x, h = blockIdx.y, b = blockIdx.z;
    const size_t rs = (size_t)HID;
    const int qr0 = qt * 64 + w * 16;

    short8 qf[4];
    {
        const ushort* qp = Q + ((size_t)(b * S) + qr0 + fr) * rs + h * 128 + fq * 8;
#pragma unroll
        for (int ks = 0; ks < 4; ++ks) qf[ks] = *(const short8*)(qp + ks * 32);
    }

    f32x4 of[8];
#pragma unroll
    for (int n = 0; n < 8; ++n) of[n] = f32x4{0.f, 0.f, 0.f, 0.f};
    float m_i[4] = {-1e30f, -1e30f, -1e30f, -1e30f};
    float l_i[4] = {0.f, 0.f, 0.f, 0.f};

    const ushort* Kb = K + (size_t)(b * S) * rs + h * 128;
    const ushort* Vb = V + (size_t)(b * S) * rs + h * 128;

    const int krow = tid >> 4;
    const int kcolb = (tid & 15) << 4;

    // V staging source offsets: LDS byte A=p*4096+w*1024+lane*16
    // -> L=p*32+w*8+(lane>>3), kv=(L>>3)*4+((lane>>1)&3), dh=(L&7)*16+(lane&1)*8
    size_t voff[4];
#pragma unroll
    for (int p = 0; p < 4; ++p) {
        int L = p * 32 + w * 8 + (lane >> 3);
        int kv = (L >> 3) * 4 + ((lane >> 1) & 3);
        int dh = (L & 7) * 16 + (lane & 1) * 8;
        voff[p] = (size_t)kv * rs + dh;
    }

    // staging helpers (4 gloads each; issue order within wave: K then V matters)
    auto stageK = [&](int t) {
#pragma unroll
        for (int j = 0; j < 4; ++j) {
            int row = j * 16 + krow;
            int lcolb = kcolb ^ ((row & 7) << 4);
            const ushort* src = Kb + (size_t)(t * 64 + row) * rs + (lcolb >> 1);
            async_copy16(src, &Ks[(j * 256 + w * 64) * 8]);
        }
    };
    auto stageV = [&](int t) {
        const ushort* vsrc = Vb + (size_t)t * 64 * rs;
#pragma unroll
        for (int p = 0; p < 4; ++p)
            async_copy16(vsrc + voff[p], &Vs[p * 2048 + w * 512]);
    };

    const int nt = S / 64;
    // prologue: stage tile 0 (K first, then V — FIFO order assumed by vmcnt counts)
    stageK(0);
    stageV(0);

    for (int t = 0; t < nt; ++t) {
        const int tp = (t + 1 < nt) ? t + 1 : t;

        // ---- wait: own K(t) in-flight <= 4 => K(t) landed; barrier => all waves ----
        asm volatile("s_waitcnt vmcnt(4)" ::: "memory");
        __builtin_amdgcn_s_barrier();
        __builtin_amdgcn_sched_barrier(0);

        // ---- S = Q K^T ----
        f32x4 sf[4];
        __builtin_amdgcn_s_setprio(1);
#pragma unroll
        for (int kc = 0; kc < 4; ++kc) {
            f32x4 s = f32x4{0.f, 0.f, 0.f, 0.f};
#pragma unroll
            for (int ks = 0; ks < 4; ++ks) {
                int row = kc * 16 + fr;
                int pb = (row * 256 + ks * 64 + fq * 16) ^ ((row & 7) << 4);
                short8 kf = *(const short8*)((const char*)Ks + pb);
                s = __builtin_amdgcn_mfma_f32_16x16x32_bf16(qf[ks], kf, s, 0, 0, 0);
            }
            sf[kc] = s * scale;
        }
        __builtin_amdgcn_s_setprio(0);

        // ---- online softmax (16-lane-group shuffle reduce) ----
        float mnew[4], sc[4], rsum[4];
#pragma unroll
        for (int r = 0; r < 4; ++r) {
            float tm = fmaxf(fmaxf(sf[0][r], sf[1][r]), fmaxf(sf[2][r], sf[3][r]));
#pragma unroll
            for (int d = 1; d < 16; d <<= 1) tm = fmaxf(tm, __shfl_xor(tm, d));
            mnew[r] = fmaxf(m_i[r], tm);
            sc[r] = __expf(m_i[r] - mnew[r]);
            rsum[r] = 0.f;
        }
#pragma unroll
        for (int kc = 0; kc < 4; ++kc)
#pragma unroll
            for (int r = 0; r < 4; ++r) {
                float p = __expf(sf[kc][r] - mnew[r]);
                sf[kc][r] = p;
                rsum[r] += p;
            }
#pragma unroll
        for (int r = 0; r < 4; ++r) {
#pragma unroll
            for (int d = 1; d < 16; d <<= 1) rsum[r] += __shfl_xor(rsum[r], d);
            l_i[r] = l_i[r] * sc[r] + rsum[r];
            m_i[r] = mnew[r];
        }
#pragma unroll
        for (int n = 0; n < 8; ++n) {
            f32x4 o = of[n];
            o[0] *= sc[0]; o[1] *= sc[1]; o[2] *= sc[2]; o[3] *= sc[3];
            of[n] = o;
        }

        // ---- wait: V(t) landed (only V(t) outstanding); barrier also => Ks free ----
        asm volatile("s_waitcnt vmcnt(0)" ::: "memory");
        __builtin_amdgcn_s_barrier();
        __builtin_amdgcn_sched_barrier(0);
        stageK(tp);   // prefetch K(t+1); waited at next tile's vmcnt(4)

        // ---- P -> bf16 -> per-wave LDS (packed, XOR-swizzled) ----
        char* pw = (char*)&Ps[w][0];
#pragma unroll
        for (int kc = 0; kc < 4; ++kc)
#pragma unroll
            for (int r = 0; r < 4; ++r) {
                int q = fq * 4 + r;
                int byte = q * 128 + ((kc * 32 + fr * 2) ^ ((q & 7) << 4));
                *(ushort*)(pw + byte) = f2bf(sf[kc][r]);
            }
        asm volatile("s_waitcnt lgkmcnt(0)" ::: "memory");
        __builtin_amdgcn_sched_barrier(0);

        // ---- O += P V  (B-fragments via hardware transpose reads) ----
        __builtin_amdgcn_s_setprio(1);
#pragma unroll
        for (int kvc = 0; kvc < 2; ++kvc) {
            int pbyte = fr * 128 + ((kvc * 64 + fq * 16) ^ ((fr & 7) << 4));
            short8 pf = *(const short8*)(pw + pbyte);
#pragma unroll
            for (int nb = 0; nb < 2; ++nb) {
                short4v vr[4][2];
#pragma unroll
                for (int nn = 0; nn < 4; ++nn)
#pragma unroll
                    for (int hf = 0; hf < 2; ++hf) {
                        int n = nb * 4 + nn;
                        int L = (kvc * 8 + fq * 2 + hf) * 8 + n;
                        vr[nn][hf] = tr16((const ushort*)((const char*)Vs + L * 128 + fr * 8));
                    }
                asm volatile("s_waitcnt lgkmcnt(0)" ::: "memory");
                __builtin_amdgcn_sched_barrier(0);
#pragma unroll
                for (int nn = 0; nn < 4; ++nn) {
                    int n = nb * 4 + nn;
                    short8 vf = __builtin_shufflevector(vr[nn][0], vr[nn][1], 0, 1, 2, 3, 4, 5, 6, 7);
                    of[n] = __builtin_amdgcn_mfma_f32_16x16x32_bf16(pf, vf, of[n], 0, 0, 0);
                }
            }
        }
        __builtin_amdgcn_s_setprio(0);

        // ---- barrier: Vs free everywhere; then prefetch V(t+1) ----
        __builtin_amdgcn_s_barrier();
        __builtin_amdgcn_sched_barrier(0);
        stageV(tp);
    }

    // drain pending DMA before LDS dealloc (cross-block LDS corruption hazard)
    asm volatile("s_waitcnt vmcnt(0)" ::: "memory");

    // ---- epilogue ----
    float inv[4];
#pragma unroll
    for (int r = 0; r < 4; ++r) inv[r] = 1.f / l_i[r];
#pragma unroll
    for (int n = 0; n < 8; ++n)
#pragma unroll
        for (int r = 0; r < 4; ++r) {
            size_t idx = ((size_t)(b * S) + qr0 + fq * 4 + r) * rs + h * 128 + n * 16 + fr;
            O[idx] = f2bf(of[n][r] * inv[r]);
        }
}

// ---------------- launch ----------------
extern "C" void kernel_launch(void* const* d_in, const int* in_sizes, int n_in,
                              void* d_out, int out_size, void* d_ws, size_t ws_size,
                              hipStream_t stream) {
    constexpr int B = 2, S = 2048, HID = 2048, H = 16;
    constexpr int M = B * S;
    const float scale = 0.08838834764831845f;

    const float* x  = (const float*)d_in[0];
    const float* wq = (const float*)d_in[1];
    const float* wk = (const float*)d_in[2];
    const float* wv = (const float*)d_in[3];
    const float* wo = (const float*)d_in[4];
    float* out = (float*)d_out;

    char* ws = (char*)d_ws;
    ushort* xb  = (ushort*)(ws);                    // [4096][2048] bf16; reused as attn out
    ushort* wqb = (ushort*)(ws + 16777216);         // wq,wk,wv casts contiguous (24 MB)
    ushort* wkb = (ushort*)(ws + 25165824);
    ushort* wvb = (ushort*)(ws + 33554432);
    ushort* qb  = (ushort*)(ws + 41943040);         // q,k,v contiguous (48 MB)
    ushort* kb  = (ushort*)(ws + 58720256);
    ushort* vb  = (ushort*)(ws + 75497472);

    const int XN = M * HID;
    const int WN = HID * HID;

    cast_kernel<<<XN / 4 / 256, 256, 0, stream>>>(x, xb, XN / 4);
    cast_kernel<<<WN / 4 / 256, 256, 0, stream>>>(wq, wqb, WN / 4);
    cast_kernel<<<WN / 4 / 256, 256, 0, stream>>>(wk, wkb, WN / 4);
    cast_kernel<<<WN / 4 / 256, 256, 0, stream>>>(wv, wvb, WN / 4);

    // fused QKV projection: one GEMM over concatenated weights -> concatenated q,k,v
    dim3 gq(3 * HID / 128, M / 128);   // (48, 32) = 1536 blocks
    gemm_bt_kernel<ushort><<<gq, 256, 0, stream>>>(xb, wqb, qb, M, HID, HID);

    dim3 ga(S / 64, H, B);             // (32, 16, 2) = 1024 blocks
    attn_kernel<<<ga, 256, 0, stream>>>(qb, kb, vb, xb, S, HID, scale);

    cast_kernel<<<WN / 4 / 256, 256, 0, stream>>>(wo, wqb, WN / 4);
    dim3 gg(HID / 128, M / 128);       // (16, 32)
    gemm_bt_kernel<float><<<gg, 256, 0, stream>>>(xb, wqb, out, M, HID, HID);
}

// Round 10
// 382.865 us; speedup vs baseline: 1.0315x; 1.0315x over previous
//
#include <hip/hip_runtime.h>
#include <hip/hip_bf16.h>
#include <stdint.h>

typedef __attribute__((ext_vector_type(8))) short short8;
typedef __attribute__((ext_vector_type(4))) short short4v;
typedef __attribute__((ext_vector_type(4))) float f32x4;
typedef __attribute__((ext_vector_type(4))) unsigned int uint4v;

static __device__ __forceinline__ ushort f2bf(float f) {
    uint32_t u = __builtin_bit_cast(uint32_t, f);
    uint32_t r = (u + 0x7FFFu + ((u >> 16) & 1u)) >> 16;
    return (ushort)r;
}

static __device__ __forceinline__ void async_copy16(const void* g, void* l) {
    __builtin_amdgcn_global_load_lds(
        (const __attribute__((address_space(1))) uint32_t*)g,
        (__attribute__((address_space(3))) uint32_t*)l, 16, 0, 0);
}

// ds_read_b64_tr_b16: tile = addr & ~127 ([4][16] bf16 row-major subtile),
// col = (addr>>3)&15; returns 4 bf16 at tile + col*2 + {0,32,64,96}.
static __device__ __forceinline__ short4v tr16(const ushort* p) {
    short4v d;
    const __attribute__((address_space(3))) ushort* p3 =
        (const __attribute__((address_space(3))) ushort*)p;
    asm volatile("ds_read_b64_tr_b16 %0, %1" : "=v"(d) : "v"(p3));
    return d;
}

// ---------------- cast fp32 -> bf16 ----------------
__global__ __launch_bounds__(256) void cast_kernel(const float* __restrict__ in,
                                                   ushort* __restrict__ out, int n4) {
    int i = blockIdx.x * 256 + threadIdx.x;
    if (i >= n4) return;
    float4 v = reinterpret_cast<const float4*>(in)[i];
    ushort4 o;
    o.x = f2bf(v.x); o.y = f2bf(v.y); o.z = f2bf(v.z); o.w = f2bf(v.w);
    reinterpret_cast<ushort4*>(out)[i] = o;
}

// ---------------- GEMM: C[M][N] = A[M][K] * B[N][K]^T (bf16 in, fp32 acc) ----------------
static __device__ __forceinline__ void store_val(float* C, size_t idx, float v) { C[idx] = v; }
static __device__ __forceinline__ void store_val(ushort* C, size_t idx, float v) { C[idx] = f2bf(v); }

template <typename OutT>
__global__ __launch_bounds__(256) void gemm_bt_kernel(const ushort* __restrict__ A,
                                                      const ushort* __restrict__ B,
                                                      OutT* __restrict__ C,
                                                      int M, int N, int K) {
    __shared__ __align__(16) ushort As[128 * 32];
    __shared__ __align__(16) ushort Bs[128 * 32];
    const int tid = threadIdx.x;
    const int w = tid >> 6, lane = tid & 63;
    const int fr = lane & 15, fq = lane >> 4;
    const int wr = w >> 1, wc = w & 1;
    const int bpn = N >> 7;
    const int which = blockIdx.x / bpn;
    const int row0 = blockIdx.y * 128;
    const int gcol0 = blockIdx.x * 128;
    const int col0 = gcol0 - which * N;
    OutT* Cw = C + (size_t)which * M * N;

    const int srow = tid >> 2;
    const int scol = (tid & 3) * 8;
    const ushort* ga0 = A + (size_t)(row0 + srow) * K + scol;
    const ushort* ga1 = A + (size_t)(row0 + 64 + srow) * K + scol;
    const ushort* gb0 = B + (size_t)(gcol0 + srow) * K + scol;
    const ushort* gb1 = B + (size_t)(gcol0 + 64 + srow) * K + scol;
    ushort* la0 = &As[(w * 64) * 8];
    ushort* la1 = &As[(256 + w * 64) * 8];
    ushort* lb0 = &Bs[(w * 64) * 8];
    ushort* lb1 = &Bs[(256 + w * 64) * 8];

    f32x4 acc[4][4];
#pragma unroll
    for (int m = 0; m < 4; ++m)
#pragma unroll
        for (int n = 0; n < 4; ++n) acc[m][n] = f32x4{0.f, 0.f, 0.f, 0.f};

    for (int kt = 0; kt < K; kt += 32) {
        __syncthreads();
        async_copy16(ga0 + kt, la0);
        async_copy16(ga1 + kt, la1);
        async_copy16(gb0 + kt, lb0);
        async_copy16(gb1 + kt, lb1);
        __syncthreads();
        short8 af[4], bfr[4];
#pragma unroll
        for (int m = 0; m < 4; ++m)
            af[m] = *(const short8*)&As[(wr * 64 + m * 16 + fr) * 32 + fq * 8];
#pragma unroll
        for (int n = 0; n < 4; ++n)
            bfr[n] = *(const short8*)&Bs[(wc * 64 + n * 16 + fr) * 32 + fq * 8];
#pragma unroll
        for (int m = 0; m < 4; ++m)
#pragma unroll
            for (int n = 0; n < 4; ++n)
                acc[m][n] = __builtin_amdgcn_mfma_f32_16x16x32_bf16(af[m], bfr[n], acc[m][n], 0, 0, 0);
    }

#pragma unroll
    for (int m = 0; m < 4; ++m) {
        const int grow = row0 + wr * 64 + m * 16 + fq * 4;
#pragma unroll
        for (int n = 0; n < 4; ++n) {
            const int gcol = col0 + wc * 64 + n * 16 + fr;
#pragma unroll
            for (int r = 0; r < 4; ++r)
                store_val(Cw, (size_t)(grow + r) * N + gcol, acc[m][n][r]);
        }
    }
}

// ---------------- flash attention fwd ----------------
// QBLK=64 (4 waves x 16 q-rows), KBLK=64. LDS 32768 B.
// Swapped QK^T: S = mfma(K,Q) -> lane holds S[kv=kc*16+fq*4+r][q=fr]:
// softmax lane-local (2 shfl_xor reduce). P redistributed in-register via
// 16 shfl + 8 selects into the PV B-fragment. PV swapped: O^T = mfma(V,P);
// of[n][r] = O[q=fr][dh=n*16+fq*4+r]. No P LDS round-trip.
__global__ __launch_bounds__(256) void attn_kernel(const ushort* __restrict__ Q,
                                                   const ushort* __restrict__ K,
                                                   const ushort* __restrict__ V,
                                                   ushort* __restrict__ O,
                                                   int S, int HID, float scale) {
    __shared__ __align__(16) ushort Ks[64 * 128];   // swz: byte ^= ((row&7)<<4)
    __shared__ __align__(16) ushort Vs[64 * 128];   // [kv/4][dh/16][4][16] subtiled

    const int tid = threadIdx.x, w = tid >> 6, lane = tid & 63;
    const int fr = lane & 15, fq = lane >> 4;
    const int qt = blockIdx.x, h = blockIdx.y, b = blockIdx.z;
    const size_t rs = (size_t)HID;
    const int qr0 = qt * 64 + w * 16;
    const float c1 = scale * 1.4426950408889634f;   // log2-domain fold

    short8 qf[4];
    {
        const ushort* qp = Q + ((size_t)(b * S) + qr0 + fr) * rs + h * 128 + fq * 8;
#pragma unroll
        for (int ks = 0; ks < 4; ++ks) qf[ks] = *(const short8*)(qp + ks * 32);
    }

    f32x4 of[8];
#pragma unroll
    for (int n = 0; n < 8; ++n) of[n] = f32x4{0.f, 0.f, 0.f, 0.f};
    float m2 = -1e30f;   // running max in log2-scaled domain
    float l = 0.f;

    const ushort* Kb = K + (size_t)(b * S) * rs + h * 128;
    const ushort* Vb = V + (size_t)(b * S) * rs + h * 128;

    const int krow = tid >> 4;
    const int kcolb = (tid & 15) << 4;

    // V staging source offsets: LDS byte A=p*4096+w*1024+lane*16
    // -> L=p*32+w*8+(lane>>3), kv=(L>>3)*4+((lane>>1)&3), dh=(L&7)*16+(lane&1)*8
    size_t voff[4];
#pragma unroll
    for (int p = 0; p < 4; ++p) {
        int L = p * 32 + w * 8 + (lane >> 3);
        int kv = (L >> 3) * 4 + ((lane >> 1) & 3);
        int dh = (L & 7) * 16 + (lane & 1) * 8;
        voff[p] = (size_t)kv * rs + dh;
    }

    // shfl source lanes for P redistribution
    const int srcA = fr + 16 * ((2 * fq) & 3);
    const int srcB = fr + 16 * ((2 * fq + 1) & 3);
    const int par = fq >> 1;   // kc parity this lane consumes

    const int nt = S / 64;
    for (int t = 0; t < nt; ++t) {
        __syncthreads();
        // ---- stage K tile (linear LDS dest, swizzled global source) ----
#pragma unroll
        for (int j = 0; j < 4; ++j) {
            int row = j * 16 + krow;
            int lcolb = kcolb ^ ((row & 7) << 4);
            const ushort* src = Kb + (size_t)(t * 64 + row) * rs + (lcolb >> 1);
            async_copy16(src, &Ks[(j * 256 + w * 64) * 8]);
        }
        // ---- stage V subtiled via global_load_lds ----
        {
            const ushort* vsrc = Vb + (size_t)t * 64 * rs;
#pragma unroll
            for (int p = 0; p < 4; ++p)
                async_copy16(vsrc + voff[p], &Vs[p * 2048 + w * 512]);
        }
        __syncthreads();

        // ---- S^T = K Q^T : lane holds S[kv=kc*16+fq*4+r][q=fr] ----
        f32x4 sf[4];
        __builtin_amdgcn_s_setprio(1);
#pragma unroll
        for (int kc = 0; kc < 4; ++kc) {
            f32x4 s = f32x4{0.f, 0.f, 0.f, 0.f};
#pragma unroll
            for (int ks = 0; ks < 4; ++ks) {
                int row = kc * 16 + fr;
                int pb = (row * 256 + ks * 64 + fq * 16) ^ ((row & 7) << 4);
                short8 kf = *(const short8*)((const char*)Ks + pb);
                s = __builtin_amdgcn_mfma_f32_16x16x32_bf16(kf, qf[ks], s, 0, 0, 0);
            }
            sf[kc] = s;   // raw scores (scale folded into exp2)
        }
        __builtin_amdgcn_s_setprio(0);

        // ---- online softmax, lane-local (q = fr) ----
        float pm = fmaxf(fmaxf(fmaxf(sf[0][0], sf[0][1]), fmaxf(sf[0][2], sf[0][3])),
                         fmaxf(fmaxf(sf[1][0], sf[1][1]), fmaxf(sf[1][2], sf[1][3])));
        pm = fmaxf(pm, fmaxf(fmaxf(fmaxf(sf[2][0], sf[2][1]), fmaxf(sf[2][2], sf[2][3])),
                             fmaxf(fmaxf(sf[3][0], sf[3][1]), fmaxf(sf[3][2], sf[3][3]))));
        pm = fmaxf(pm, __shfl_xor(pm, 16));
        pm = fmaxf(pm, __shfl_xor(pm, 32));
        float m2new = fmaxf(m2, pm * c1);
        float sc = exp2f(m2 - m2new);
        m2 = m2new;
        float rsum = 0.f;
#pragma unroll
        for (int kc = 0; kc < 4; ++kc)
#pragma unroll
            for (int r = 0; r < 4; ++r) {
                float p = exp2f(sf[kc][r] * c1 - m2);
                sf[kc][r] = p;
                rsum += p;
            }
        rsum += __shfl_xor(rsum, 16);
        rsum += __shfl_xor(rsum, 32);
        l = l * sc + rsum;
#pragma unroll
        for (int n = 0; n < 8; ++n) {
            f32x4 o = of[n];
            o[0] *= sc; o[1] *= sc; o[2] *= sc; o[3] *= sc;
            of[n] = o;
        }

        // ---- pack P pairs to bf16 dwords: cpk[kc][h] = {p[2h], p[2h+1]} ----
        uint32_t cpk[4][2];
#pragma unroll
        for (int kc = 0; kc < 4; ++kc)
#pragma unroll
            for (int hh = 0; hh < 2; ++hh)
                cpk[kc][hh] = (uint32_t)f2bf(sf[kc][2 * hh]) |
                              ((uint32_t)f2bf(sf[kc][2 * hh + 1]) << 16);

        // ---- O^T += V^T P : pf built in-register via shfl redistribution ----
        __builtin_amdgcn_s_setprio(1);
#pragma unroll
        for (int kvc = 0; kvc < 2; ++kvc) {
            uint32_t eA0 = __shfl(cpk[2 * kvc][0], srcA);
            uint32_t eA1 = __shfl(cpk[2 * kvc][1], srcA);
            uint32_t oA0 = __shfl(cpk[2 * kvc + 1][0], srcA);
            uint32_t oA1 = __shfl(cpk[2 * kvc + 1][1], srcA);
            uint32_t eB0 = __shfl(cpk[2 * kvc][0], srcB);
            uint32_t eB1 = __shfl(cpk[2 * kvc][1], srcB);
            uint32_t oB0 = __shfl(cpk[2 * kvc + 1][0], srcB);
            uint32_t oB1 = __shfl(cpk[2 * kvc + 1][1], srcB);
            uint4v pd;
            pd[0] = par ? oA0 : eA0;
            pd[1] = par ? oA1 : eA1;
            pd[2] = par ? oB0 : eB0;
            pd[3] = par ? oB1 : eB1;
            short8 pf = __builtin_bit_cast(short8, pd);
#pragma unroll
            for (int nb = 0; nb < 2; ++nb) {
                short4v vr[4][2];
#pragma unroll
                for (int nn = 0; nn < 4; ++nn)
#pragma unroll
                    for (int hf = 0; hf < 2; ++hf) {
                        int n = nb * 4 + nn;
                        int L = (kvc * 8 + fq * 2 + hf) * 8 + n;
                        vr[nn][hf] = tr16((const ushort*)((const char*)Vs + L * 128 + fr * 8));
                    }
                asm volatile("s_waitcnt lgkmcnt(0)" ::: "memory");
                __builtin_amdgcn_sched_barrier(0);
#pragma unroll
                for (int nn = 0; nn < 4; ++nn) {
                    int n = nb * 4 + nn;
                    short8 vf = __builtin_shufflevector(vr[nn][0], vr[nn][1], 0, 1, 2, 3, 4, 5, 6, 7);
                    of[n] = __builtin_amdgcn_mfma_f32_16x16x32_bf16(vf, pf, of[n], 0, 0, 0);
                }
            }
        }
        __builtin_amdgcn_s_setprio(0);
    }

    // ---- epilogue: lane owns q=qr0+fr; of[n][r] = O[q][dh=n*16+fq*4+r] ----
    float inv = 1.f / l;
    ushort* ob = O + ((size_t)(b * S) + qr0 + fr) * rs + h * 128 + fq * 4;
#pragma unroll
    for (int n = 0; n < 8; ++n) {
        ushort4 o4;
        o4.x = f2bf(of[n][0] * inv);
        o4.y = f2bf(of[n][1] * inv);
        o4.z = f2bf(of[n][2] * inv);
        o4.w = f2bf(of[n][3] * inv);
        *reinterpret_cast<ushort4*>(ob + n * 16) = o4;
    }
}

// ---------------- launch ----------------
extern "C" void kernel_launch(void* const* d_in, const int* in_sizes, int n_in,
                              void* d_out, int out_size, void* d_ws, size_t ws_size,
                              hipStream_t stream) {
    constexpr int B = 2, S = 2048, HID = 2048, H = 16;
    constexpr int M = B * S;
    const float scale = 0.08838834764831845f;

    const float* x  = (const float*)d_in[0];
    const float* wq = (const float*)d_in[1];
    const float* wk = (const float*)d_in[2];
    const float* wv = (const float*)d_in[3];
    const float* wo = (const float*)d_in[4];
    float* out = (float*)d_out;

    char* ws = (char*)d_ws;
    ushort* xb  = (ushort*)(ws);                    // [4096][2048] bf16; reused as attn out
    ushort* wqb = (ushort*)(ws + 16777216);         // wq,wk,wv casts contiguous (24 MB)
    ushort* wkb = (ushort*)(ws + 25165824);
    ushort* wvb = (ushort*)(ws + 33554432);
    ushort* qb  = (ushort*)(ws + 41943040);         // q,k,v contiguous (48 MB)
    ushort* kb  = (ushort*)(ws + 58720256);
    ushort* vb  = (ushort*)(ws + 75497472);

    const int XN = M * HID;
    const int WN = HID * HID;

    cast_kernel<<<XN / 4 / 256, 256, 0, stream>>>(x, xb, XN / 4);
    cast_kernel<<<WN / 4 / 256, 256, 0, stream>>>(wq, wqb, WN / 4);
    cast_kernel<<<WN / 4 / 256, 256, 0, stream>>>(wk, wkb, WN / 4);
    cast_kernel<<<WN / 4 / 256, 256, 0, stream>>>(wv, wvb, WN / 4);

    // fused QKV projection: one GEMM over concatenated weights -> concatenated q,k,v
    dim3 gq(3 * HID / 128, M / 128);   // (48, 32) = 1536 blocks
    gemm_bt_kernel<ushort><<<gq, 256, 0, stream>>>(xb, wqb, qb, M, HID, HID);

    dim3 ga(S / 64, H, B);             // (32, 16, 2) = 1024 blocks
    attn_kernel<<<ga, 256, 0, stream>>>(qb, kb, vb, xb, S, HID, scale);

    cast_kernel<<<WN / 4 / 256, 256, 0, stream>>>(wo, wqb, WN / 4);
    dim3 gg(HID / 128, M / 128);       // (16, 32)
    gemm_bt_kernel<float><<<gg, 256, 0, stream>>>(xb, wqb, out, M, HID, HID);
}

// Round 11
// 378.111 us; speedup vs baseline: 1.0445x; 1.0126x over previous
//
#include <hip/hip_runtime.h>
#include <hip/hip_bf16.h>
#include <stdint.h>

typedef __attribute__((ext_vector_type(8))) short short8;
typedef __attribute__((ext_vector_type(4))) short short4v;
typedef __attribute__((ext_vector_type(4))) float f32x4;
typedef __attribute__((ext_vector_type(4))) unsigned int uint4v;

static __device__ __forceinline__ ushort f2bf(float f) {
    uint32_t u = __builtin_bit_cast(uint32_t, f);
    uint32_t r = (u + 0x7FFFu + ((u >> 16) & 1u)) >> 16;
    return (ushort)r;
}

static __device__ __forceinline__ uint32_t cvt_pk_bf16(float lo, float hi) {
    uint32_t d;
    asm("v_cvt_pk_bf16_f32 %0, %1, %2" : "=v"(d) : "v"(lo), "v"(hi));
    return d;
}

static __device__ __forceinline__ void async_copy16(const void* g, void* l) {
    __builtin_amdgcn_global_load_lds(
        (const __attribute__((address_space(1))) uint32_t*)g,
        (__attribute__((address_space(3))) uint32_t*)l, 16, 0, 0);
}

// ds_read_b64_tr_b16: tile = addr & ~127 ([4][16] bf16 row-major subtile),
// col = (addr>>3)&15; returns 4 bf16 at tile + col*2 + {0,32,64,96}.
static __device__ __forceinline__ short4v tr16(const ushort* p) {
    short4v d;
    const __attribute__((address_space(3))) ushort* p3 =
        (const __attribute__((address_space(3))) ushort*)p;
    asm volatile("ds_read_b64_tr_b16 %0, %1" : "=v"(d) : "v"(p3));
    return d;
}

// ---------------- cast fp32 -> bf16 ----------------
__global__ __launch_bounds__(256) void cast_kernel(const float* __restrict__ in,
                                                   ushort* __restrict__ out, int n4) {
    int i = blockIdx.x * 256 + threadIdx.x;
    if (i >= n4) return;
    float4 v = reinterpret_cast<const float4*>(in)[i];
    uint32_t d0 = cvt_pk_bf16(v.x, v.y);
    uint32_t d1 = cvt_pk_bf16(v.z, v.w);
    uint2 o; o.x = d0; o.y = d1;
    reinterpret_cast<uint2*>(out)[i] = o;
}

// cast 3 equal-size fp32 buffers into one contiguous bf16 region
__global__ __launch_bounds__(256) void cast3_kernel(const float* __restrict__ a,
                                                    const float* __restrict__ b,
                                                    const float* __restrict__ c,
                                                    ushort* __restrict__ out, int n4each) {
    int i = blockIdx.x * 256 + threadIdx.x;
    int which = i / n4each;
    int j = i - which * n4each;
    const float* src = which == 0 ? a : (which == 1 ? b : c);
    if (which > 2) return;
    float4 v = reinterpret_cast<const float4*>(src)[j];
    uint2 o;
    o.x = cvt_pk_bf16(v.x, v.y);
    o.y = cvt_pk_bf16(v.z, v.w);
    reinterpret_cast<uint2*>(out)[i] = o;
}

// ---------------- GEMM: C[M][N] = A[M][K] * B[N][K]^T (bf16 in, fp32 acc) ----------------
static __device__ __forceinline__ void store_val(float* C, size_t idx, float v) { C[idx] = v; }
static __device__ __forceinline__ void store_val(ushort* C, size_t idx, float v) { C[idx] = f2bf(v); }

template <typename OutT>
__global__ __launch_bounds__(256) void gemm_bt_kernel(const ushort* __restrict__ A,
                                                      const ushort* __restrict__ B,
                                                      OutT* __restrict__ C,
                                                      int M, int N, int K) {
    __shared__ __align__(16) ushort As[128 * 32];
    __shared__ __align__(16) ushort Bs[128 * 32];
    const int tid = threadIdx.x;
    const int w = tid >> 6, lane = tid & 63;
    const int fr = lane & 15, fq = lane >> 4;
    const int wr = w >> 1, wc = w & 1;
    const int bpn = N >> 7;
    const int which = blockIdx.x / bpn;
    const int row0 = blockIdx.y * 128;
    const int gcol0 = blockIdx.x * 128;
    const int col0 = gcol0 - which * N;
    OutT* Cw = C + (size_t)which * M * N;

    const int srow = tid >> 2;
    const int scol = (tid & 3) * 8;
    const ushort* ga0 = A + (size_t)(row0 + srow) * K + scol;
    const ushort* ga1 = A + (size_t)(row0 + 64 + srow) * K + scol;
    const ushort* gb0 = B + (size_t)(gcol0 + srow) * K + scol;
    const ushort* gb1 = B + (size_t)(gcol0 + 64 + srow) * K + scol;
    ushort* la0 = &As[(w * 64) * 8];
    ushort* la1 = &As[(256 + w * 64) * 8];
    ushort* lb0 = &Bs[(w * 64) * 8];
    ushort* lb1 = &Bs[(256 + w * 64) * 8];

    f32x4 acc[4][4];
#pragma unroll
    for (int m = 0; m < 4; ++m)
#pragma unroll
        for (int n = 0; n < 4; ++n) acc[m][n] = f32x4{0.f, 0.f, 0.f, 0.f};

    for (int kt = 0; kt < K; kt += 32) {
        __syncthreads();
        async_copy16(ga0 + kt, la0);
        async_copy16(ga1 + kt, la1);
        async_copy16(gb0 + kt, lb0);
        async_copy16(gb1 + kt, lb1);
        __syncthreads();
        short8 af[4], bfr[4];
#pragma unroll
        for (int m = 0; m < 4; ++m)
            af[m] = *(const short8*)&As[(wr * 64 + m * 16 + fr) * 32 + fq * 8];
#pragma unroll
        for (int n = 0; n < 4; ++n)
            bfr[n] = *(const short8*)&Bs[(wc * 64 + n * 16 + fr) * 32 + fq * 8];
#pragma unroll
        for (int m = 0; m < 4; ++m)
#pragma unroll
            for (int n = 0; n < 4; ++n)
                acc[m][n] = __builtin_amdgcn_mfma_f32_16x16x32_bf16(af[m], bfr[n], acc[m][n], 0, 0, 0);
    }

#pragma unroll
    for (int m = 0; m < 4; ++m) {
        const int grow = row0 + wr * 64 + m * 16 + fq * 4;
#pragma unroll
        for (int n = 0; n < 4; ++n) {
            const int gcol = col0 + wc * 64 + n * 16 + fr;
#pragma unroll
            for (int r = 0; r < 4; ++r)
                store_val(Cw, (size_t)(grow + r) * N + gcol, acc[m][n][r]);
        }
    }
}

// ---------------- flash attention fwd ----------------
// QBLK=64 (4 waves x 16 q-rows), KBLK=64. LDS 32768 B.
// Swapped QK^T (lane-local softmax), in-register P redistribution (shfl),
// swapped PV via tr16. T12 cvt_pk packing + T13 defer-max (THR=8, log2 dom).
__global__ __launch_bounds__(256) void attn_kernel(const ushort* __restrict__ Q,
                                                   const ushort* __restrict__ K,
                                                   const ushort* __restrict__ V,
                                                   ushort* __restrict__ O,
                                                   int S, int HID, float scale) {
    __shared__ __align__(16) ushort Ks[64 * 128];   // swz: byte ^= ((row&7)<<4)
    __shared__ __align__(16) ushort Vs[64 * 128];   // [kv/4][dh/16][4][16] subtiled

    const int tid = threadIdx.x, w = tid >> 6, lane = tid & 63;
    const int fr = lane & 15, fq = lane >> 4;
    const int qt = blockIdx.x, h = blockIdx.y, b = blockIdx.z;
    const size_t rs = (size_t)HID;
    const int qr0 = qt * 64 + w * 16;
    const float c1 = scale * 1.4426950408889634f;   // log2-domain fold

    short8 qf[4];
    {
        const ushort* qp = Q + ((size_t)(b * S) + qr0 + fr) * rs + h * 128 + fq * 8;
#pragma unroll
        for (int ks = 0; ks < 4; ++ks) qf[ks] = *(const short8*)(qp + ks * 32);
    }

    f32x4 of[8];
#pragma unroll
    for (int n = 0; n < 8; ++n) of[n] = f32x4{0.f, 0.f, 0.f, 0.f};
    float m2 = -1e30f;   // running max, log2-scaled domain
    float l = 0.f;

    const ushort* Kb = K + (size_t)(b * S) * rs + h * 128;
    const ushort* Vb = V + (size_t)(b * S) * rs + h * 128;

    const int krow = tid >> 4;
    const int kcolb = (tid & 15) << 4;

    // V staging source offsets: LDS byte A=p*4096+w*1024+lane*16
    // -> L=p*32+w*8+(lane>>3), kv=(L>>3)*4+((lane>>1)&3), dh=(L&7)*16+(lane&1)*8
    size_t voff[4];
#pragma unroll
    for (int p = 0; p < 4; ++p) {
        int L = p * 32 + w * 8 + (lane >> 3);
        int kv = (L >> 3) * 4 + ((lane >> 1) & 3);
        int dh = (L & 7) * 16 + (lane & 1) * 8;
        voff[p] = (size_t)kv * rs + dh;
    }

    // shfl source lanes for P redistribution
    const int srcA = fr + 16 * ((2 * fq) & 3);
    const int srcB = fr + 16 * ((2 * fq + 1) & 3);
    const int par = fq >> 1;

    const int nt = S / 64;
    for (int t = 0; t < nt; ++t) {
        __syncthreads();
        // ---- stage K tile (linear LDS dest, swizzled global source) ----
#pragma unroll
        for (int j = 0; j < 4; ++j) {
            int row = j * 16 + krow;
            int lcolb = kcolb ^ ((row & 7) << 4);
            const ushort* src = Kb + (size_t)(t * 64 + row) * rs + (lcolb >> 1);
            async_copy16(src, &Ks[(j * 256 + w * 64) * 8]);
        }
        // ---- stage V subtiled via global_load_lds ----
        {
            const ushort* vsrc = Vb + (size_t)t * 64 * rs;
#pragma unroll
            for (int p = 0; p < 4; ++p)
                async_copy16(vsrc + voff[p], &Vs[p * 2048 + w * 512]);
        }
        __syncthreads();

        // ---- S^T = K Q^T : lane holds S[kv=kc*16+fq*4+r][q=fr] ----
        f32x4 sf[4];
        __builtin_amdgcn_s_setprio(1);
#pragma unroll
        for (int kc = 0; kc < 4; ++kc) {
            f32x4 s = f32x4{0.f, 0.f, 0.f, 0.f};
#pragma unroll
            for (int ks = 0; ks < 4; ++ks) {
                int row = kc * 16 + fr;
                int pb = (row * 256 + ks * 64 + fq * 16) ^ ((row & 7) << 4);
                short8 kf = *(const short8*)((const char*)Ks + pb);
                s = __builtin_amdgcn_mfma_f32_16x16x32_bf16(kf, qf[ks], s, 0, 0, 0);
            }
            sf[kc] = s;
        }
        __builtin_amdgcn_s_setprio(0);

        // ---- online softmax, lane-local (q = fr), defer-max THR=8 ----
        float pm = fmaxf(fmaxf(fmaxf(sf[0][0], sf[0][1]), fmaxf(sf[0][2], sf[0][3])),
                         fmaxf(fmaxf(sf[1][0], sf[1][1]), fmaxf(sf[1][2], sf[1][3])));
        pm = fmaxf(pm, fmaxf(fmaxf(fmaxf(sf[2][0], sf[2][1]), fmaxf(sf[2][2], sf[2][3])),
                             fmaxf(fmaxf(sf[3][0], sf[3][1]), fmaxf(sf[3][2], sf[3][3]))));
        pm = fmaxf(pm, __shfl_xor(pm, 16));
        pm = fmaxf(pm, __shfl_xor(pm, 32));
        float pm2 = pm * c1;
        const bool noresc = __all(pm2 - m2 <= 8.0f);
        float sc = 1.0f;
        if (!noresc) {
            float m2new = fmaxf(m2, pm2);
            sc = exp2f(m2 - m2new);
            m2 = m2new;
        }
        float rsum = 0.f;
#pragma unroll
        for (int kc = 0; kc < 4; ++kc)
#pragma unroll
            for (int r = 0; r < 4; ++r) {
                float p = exp2f(sf[kc][r] * c1 - m2);
                sf[kc][r] = p;
                rsum += p;
            }
        rsum += __shfl_xor(rsum, 16);
        rsum += __shfl_xor(rsum, 32);
        if (noresc) {
            l = l + rsum;
        } else {
            l = l * sc + rsum;
#pragma unroll
            for (int n = 0; n < 8; ++n) {
                f32x4 o = of[n];
                o[0] *= sc; o[1] *= sc; o[2] *= sc; o[3] *= sc;
                of[n] = o;
            }
        }

        // ---- pack P pairs to bf16 dwords via v_cvt_pk_bf16_f32 (T12) ----
        uint32_t cpk[4][2];
#pragma unroll
        for (int kc = 0; kc < 4; ++kc)
#pragma unroll
            for (int hh = 0; hh < 2; ++hh)
                cpk[kc][hh] = cvt_pk_bf16(sf[kc][2 * hh], sf[kc][2 * hh + 1]);

        // ---- O^T += V^T P : pf built in-register via shfl redistribution ----
        __builtin_amdgcn_s_setprio(1);
#pragma unroll
        for (int kvc = 0; kvc < 2; ++kvc) {
            uint32_t eA0 = __shfl(cpk[2 * kvc][0], srcA);
            uint32_t eA1 = __shfl(cpk[2 * kvc][1], srcA);
            uint32_t oA0 = __shfl(cpk[2 * kvc + 1][0], srcA);
            uint32_t oA1 = __shfl(cpk[2 * kvc + 1][1], srcA);
            uint32_t eB0 = __shfl(cpk[2 * kvc][0], srcB);
            uint32_t eB1 = __shfl(cpk[2 * kvc][1], srcB);
            uint32_t oB0 = __shfl(cpk[2 * kvc + 1][0], srcB);
            uint32_t oB1 = __shfl(cpk[2 * kvc + 1][1], srcB);
            uint4v pd;
            pd[0] = par ? oA0 : eA0;
            pd[1] = par ? oA1 : eA1;
            pd[2] = par ? oB0 : eB0;
            pd[3] = par ? oB1 : eB1;
            short8 pf = __builtin_bit_cast(short8, pd);
#pragma unroll
            for (int nb = 0; nb < 2; ++nb) {
                short4v vr[4][2];
#pragma unroll
                for (int nn = 0; nn < 4; ++nn)
#pragma unroll
                    for (int hf = 0; hf < 2; ++hf) {
                        int n = nb * 4 + nn;
                        int L = (kvc * 8 + fq * 2 + hf) * 8 + n;
                        vr[nn][hf] = tr16((const ushort*)((const char*)Vs + L * 128 + fr * 8));
                    }
                asm volatile("s_waitcnt lgkmcnt(0)" ::: "memory");
                __builtin_amdgcn_sched_barrier(0);
#pragma unroll
                for (int nn = 0; nn < 4; ++nn) {
                    int n = nb * 4 + nn;
                    short8 vf = __builtin_shufflevector(vr[nn][0], vr[nn][1], 0, 1, 2, 3, 4, 5, 6, 7);
                    of[n] = __builtin_amdgcn_mfma_f32_16x16x32_bf16(vf, pf, of[n], 0, 0, 0);
                }
            }
        }
        __builtin_amdgcn_s_setprio(0);
    }

    // ---- epilogue: lane owns q=qr0+fr; of[n][r] = O[q][dh=n*16+fq*4+r] ----
    float inv = 1.f / l;
    ushort* ob = O + ((size_t)(b * S) + qr0 + fr) * rs + h * 128 + fq * 4;
#pragma unroll
    for (int n = 0; n < 8; ++n) {
        uint2 o2;
        o2.x = cvt_pk_bf16(of[n][0] * inv, of[n][1] * inv);
        o2.y = cvt_pk_bf16(of[n][2] * inv, of[n][3] * inv);
        *reinterpret_cast<uint2*>(ob + n * 16) = o2;
    }
}

// ---------------- launch ----------------
extern "C" void kernel_launch(void* const* d_in, const int* in_sizes, int n_in,
                              void* d_out, int out_size, void* d_ws, size_t ws_size,
                              hipStream_t stream) {
    constexpr int B = 2, S = 2048, HID = 2048, H = 16;
    constexpr int M = B * S;
    const float scale = 0.08838834764831845f;

    const float* x  = (const float*)d_in[0];
    const float* wq = (const float*)d_in[1];
    const float* wk = (const float*)d_in[2];
    const float* wv = (const float*)d_in[3];
    const float* wo = (const float*)d_in[4];
    float* out = (float*)d_out;

    char* ws = (char*)d_ws;
    ushort* xb  = (ushort*)(ws);                    // [4096][2048] bf16; reused as attn out
    ushort* wqb = (ushort*)(ws + 16777216);         // wq,wk,wv casts contiguous (24 MB)
    ushort* qb  = (ushort*)(ws + 41943040);         // q,k,v contiguous (48 MB)
    ushort* kb  = (ushort*)(ws + 58720256);
    ushort* vb  = (ushort*)(ws + 75497472);

    const int XN = M * HID;
    const int WN = HID * HID;

    cast_kernel<<<XN / 4 / 256, 256, 0, stream>>>(x, xb, XN / 4);
    cast3_kernel<<<3 * WN / 4 / 256, 256, 0, stream>>>(wq, wk, wv, wqb, WN / 4);

    // fused QKV projection: one GEMM over concatenated weights -> concatenated q,k,v
    dim3 gq(3 * HID / 128, M / 128);   // (48, 32) = 1536 blocks
    gemm_bt_kernel<ushort><<<gq, 256, 0, stream>>>(xb, wqb, qb, M, HID, HID);

    dim3 ga(S / 64, H, B);             // (32, 16, 2) = 1024 blocks
    attn_kernel<<<ga, 256, 0, stream>>>(qb, kb, vb, xb, S, HID, scale);

    cast_kernel<<<WN / 4 / 256, 256, 0, stream>>>(wo, wqb, WN / 4);
    dim3 gg(HID / 128, M / 128);       // (16, 32)
    gemm_bt_kernel<float><<<gg, 256, 0, stream>>>(xb, wqb, out, M, HID, HID);
}

// Round 12
// 338.757 us; speedup vs baseline: 1.1658x; 1.1162x over previous
//
#include <hip/hip_runtime.h>
#include <hip/hip_bf16.h>
#include <stdint.h>

typedef __attribute__((ext_vector_type(8))) short short8;
typedef __attribute__((ext_vector_type(4))) short short4v;
typedef __attribute__((ext_vector_type(4))) float f32x4;
typedef __attribute__((ext_vector_type(4))) unsigned int uint4v;

static __device__ __forceinline__ ushort f2bf(float f) {
    uint32_t u = __builtin_bit_cast(uint32_t, f);
    uint32_t r = (u + 0x7FFFu + ((u >> 16) & 1u)) >> 16;
    return (ushort)r;
}

static __device__ __forceinline__ uint32_t cvt_pk_bf16(float lo, float hi) {
    uint32_t d;
    asm("v_cvt_pk_bf16_f32 %0, %1, %2" : "=v"(d) : "v"(lo), "v"(hi));
    return d;
}

static __device__ __forceinline__ void async_copy16(const void* g, void* l) {
    __builtin_amdgcn_global_load_lds(
        (const __attribute__((address_space(1))) uint32_t*)g,
        (__attribute__((address_space(3))) uint32_t*)l, 16, 0, 0);
}

// ds_read_b64_tr_b16 at base + literal offset. tile = addr & ~127
// ([4][16] bf16 row-major subtile), col = (addr>>3)&15;
// returns 4 bf16 at tile + col*2 + {0,32,64,96}.
#define TR16(P3, IMM)                                                        \
    ({                                                                       \
        short4v _d;                                                          \
        asm volatile("ds_read_b64_tr_b16 %0, %1 offset:" #IMM                \
                     : "=v"(_d) : "v"(P3));                                  \
        _d;                                                                  \
    })

#define CAT8(a, b) __builtin_shufflevector(a, b, 0, 1, 2, 3, 4, 5, 6, 7)

// ---------------- cast fp32 -> bf16 ----------------
__global__ __launch_bounds__(256) void cast_kernel(const float* __restrict__ in,
                                                   ushort* __restrict__ out, int n4) {
    int i = blockIdx.x * 256 + threadIdx.x;
    if (i >= n4) return;
    float4 v = reinterpret_cast<const float4*>(in)[i];
    uint2 o;
    o.x = cvt_pk_bf16(v.x, v.y);
    o.y = cvt_pk_bf16(v.z, v.w);
    reinterpret_cast<uint2*>(out)[i] = o;
}

// cast 3 equal-size fp32 buffers into one contiguous bf16 region
__global__ __launch_bounds__(256) void cast3_kernel(const float* __restrict__ a,
                                                    const float* __restrict__ b,
                                                    const float* __restrict__ c,
                                                    ushort* __restrict__ out, int n4each) {
    int i = blockIdx.x * 256 + threadIdx.x;
    int which = i / n4each;
    int j = i - which * n4each;
    const float* src = which == 0 ? a : (which == 1 ? b : c);
    if (which > 2) return;
    float4 v = reinterpret_cast<const float4*>(src)[j];
    uint2 o;
    o.x = cvt_pk_bf16(v.x, v.y);
    o.y = cvt_pk_bf16(v.z, v.w);
    reinterpret_cast<uint2*>(out)[i] = o;
}

// ---------------- GEMM: C[M][N] = A[M][K] * B[N][K]^T (bf16 in, fp32 acc) ----------------
static __device__ __forceinline__ void store_val(float* C, size_t idx, float v) { C[idx] = v; }
static __device__ __forceinline__ void store_val(ushort* C, size_t idx, float v) { C[idx] = f2bf(v); }

template <typename OutT>
__global__ __launch_bounds__(256) void gemm_bt_kernel(const ushort* __restrict__ A,
                                                      const ushort* __restrict__ B,
                                                      OutT* __restrict__ C,
                                                      int M, int N, int K) {
    __shared__ __align__(16) ushort As[128 * 32];
    __shared__ __align__(16) ushort Bs[128 * 32];
    const int tid = threadIdx.x;
    const int w = tid >> 6, lane = tid & 63;
    const int fr = lane & 15, fq = lane >> 4;
    const int wr = w >> 1, wc = w & 1;
    const int bpn = N >> 7;
    const int which = blockIdx.x / bpn;
    const int row0 = blockIdx.y * 128;
    const int gcol0 = blockIdx.x * 128;
    const int col0 = gcol0 - which * N;
    OutT* Cw = C + (size_t)which * M * N;

    const int srow = tid >> 2;
    const int scol = (tid & 3) * 8;
    const ushort* ga0 = A + (size_t)(row0 + srow) * K + scol;
    const ushort* ga1 = A + (size_t)(row0 + 64 + srow) * K + scol;
    const ushort* gb0 = B + (size_t)(gcol0 + srow) * K + scol;
    const ushort* gb1 = B + (size_t)(gcol0 + 64 + srow) * K + scol;
    ushort* la0 = &As[(w * 64) * 8];
    ushort* la1 = &As[(256 + w * 64) * 8];
    ushort* lb0 = &Bs[(w * 64) * 8];
    ushort* lb1 = &Bs[(256 + w * 64) * 8];

    f32x4 acc[4][4];
#pragma unroll
    for (int m = 0; m < 4; ++m)
#pragma unroll
        for (int n = 0; n < 4; ++n) acc[m][n] = f32x4{0.f, 0.f, 0.f, 0.f};

    for (int kt = 0; kt < K; kt += 32) {
        __syncthreads();
        async_copy16(ga0 + kt, la0);
        async_copy16(ga1 + kt, la1);
        async_copy16(gb0 + kt, lb0);
        async_copy16(gb1 + kt, lb1);
        __syncthreads();
        short8 af[4], bfr[4];
#pragma unroll
        for (int m = 0; m < 4; ++m)
            af[m] = *(const short8*)&As[(wr * 64 + m * 16 + fr) * 32 + fq * 8];
#pragma unroll
        for (int n = 0; n < 4; ++n)
            bfr[n] = *(const short8*)&Bs[(wc * 64 + n * 16 + fr) * 32 + fq * 8];
#pragma unroll
        for (int m = 0; m < 4; ++m)
#pragma unroll
            for (int n = 0; n < 4; ++n)
                acc[m][n] = __builtin_amdgcn_mfma_f32_16x16x32_bf16(af[m], bfr[n], acc[m][n], 0, 0, 0);
    }

#pragma unroll
    for (int m = 0; m < 4; ++m) {
        const int grow = row0 + wr * 64 + m * 16 + fq * 4;
#pragma unroll
        for (int n = 0; n < 4; ++n) {
            const int gcol = col0 + wc * 64 + n * 16 + fr;
#pragma unroll
            for (int r = 0; r < 4; ++r)
                store_val(Cw, (size_t)(grow + r) * N + gcol, acc[m][n][r]);
        }
    }
}

// ---------------- flash attention fwd ----------------
// 8 waves x 16 q-rows = QBLK 128/block (512 thr); KBLK=64; LDS 32768 B.
// K/V staged ONCE per 128 q-rows (half the staging of the 4-wave version).
// Swapped QK^T (lane-local softmax), in-reg P redistribution, swapped PV via
// tr16 with single base VGPR + literal offsets. cvt_pk packing; defer-max.
__global__ __launch_bounds__(512) void attn_kernel(const ushort* __restrict__ Q,
                                                   const ushort* __restrict__ K,
                                                   const ushort* __restrict__ V,
                                                   ushort* __restrict__ O,
                                                   int S, int HID, float scale) {
    __shared__ __align__(16) ushort Ks[64 * 128];   // swz: byte ^= ((row&7)<<4)
    __shared__ __align__(16) ushort Vs[64 * 128];   // [kv/4][dh/16][4][16] subtiled

    const int tid = threadIdx.x, w = tid >> 6, lane = tid & 63;
    const int fr = lane & 15, fq = lane >> 4;
    const int qt = blockIdx.x, h = blockIdx.y, b = blockIdx.z;
    const size_t rs = (size_t)HID;
    const int qr0 = qt * 128 + w * 16;
    const float c1 = scale * 1.4426950408889634f;

    short8 qf[4];
    {
        const ushort* qp = Q + ((size_t)(b * S) + qr0 + fr) * rs + h * 128 + fq * 8;
#pragma unroll
        for (int ks = 0; ks < 4; ++ks) qf[ks] = *(const short8*)(qp + ks * 32);
    }

    f32x4 of[8];
#pragma unroll
    for (int n = 0; n < 8; ++n) of[n] = f32x4{0.f, 0.f, 0.f, 0.f};
    float m2 = -1e30f;
    float l = 0.f;

    const ushort* Kb = K + (size_t)(b * S) * rs + h * 128;
    const ushort* Vb = V + (size_t)(b * S) * rs + h * 128;

    // K staging (2 gloads): round j covers rows j*32 + w*4 + (lane>>4)
    size_t koff[2];
#pragma unroll
    for (int j = 0; j < 2; ++j) {
        int row = j * 32 + w * 4 + (lane >> 4);
        int colb = ((lane & 15) * 16) ^ ((row & 7) << 4);
        koff[j] = (size_t)row * rs + (colb >> 1);
    }
    // V staging (2 gloads): LDS byte A=j*8192+w*1024+lane*16 -> subtile L=A>>7
    size_t voff[2];
#pragma unroll
    for (int j = 0; j < 2; ++j) {
        int L = j * 64 + w * 8 + (lane >> 3);
        int kv = (L >> 3) * 4 + ((lane >> 1) & 3);
        int dh = (L & 7) * 16 + (lane & 1) * 8;
        voff[j] = (size_t)kv * rs + dh;
    }

    // tr16 base: addr = base + (kvc*8192 + hf*1024 + n*128) literal
    const __attribute__((address_space(3))) ushort* vb3 =
        (const __attribute__((address_space(3))) ushort*)((const char*)Vs + fq * 2048 + fr * 8);

    // shfl source lanes for P redistribution
    const int srcA = fr + 16 * ((2 * fq) & 3);
    const int srcB = fr + 16 * ((2 * fq + 1) & 3);
    const int par = fq >> 1;

    const int nt = S / 64;
    for (int t = 0; t < nt; ++t) {
        __syncthreads();
        const ushort* kt0 = Kb + (size_t)t * 64 * rs;
        const ushort* vt0 = Vb + (size_t)t * 64 * rs;
#pragma unroll
        for (int j = 0; j < 2; ++j)
            async_copy16(kt0 + koff[j], &Ks[j * 4096 + w * 512]);
#pragma unroll
        for (int j = 0; j < 2; ++j)
            async_copy16(vt0 + voff[j], &Vs[j * 4096 + w * 512]);
        __syncthreads();

        // ---- S^T = K Q^T : lane holds S[kv=kc*16+fq*4+r][q=fr] ----
        f32x4 sf[4];
        __builtin_amdgcn_s_setprio(1);
#pragma unroll
        for (int kc = 0; kc < 4; ++kc) {
            f32x4 s = f32x4{0.f, 0.f, 0.f, 0.f};
#pragma unroll
            for (int ks = 0; ks < 4; ++ks) {
                int row = kc * 16 + fr;
                int pb = (row * 256 + ks * 64 + fq * 16) ^ ((row & 7) << 4);
                short8 kf = *(const short8*)((const char*)Ks + pb);
                s = __builtin_amdgcn_mfma_f32_16x16x32_bf16(kf, qf[ks], s, 0, 0, 0);
            }
            sf[kc] = s;
        }
        __builtin_amdgcn_s_setprio(0);

        // ---- online softmax, lane-local (q = fr), defer-max THR=8 ----
        float pm = fmaxf(fmaxf(fmaxf(sf[0][0], sf[0][1]), fmaxf(sf[0][2], sf[0][3])),
                         fmaxf(fmaxf(sf[1][0], sf[1][1]), fmaxf(sf[1][2], sf[1][3])));
        pm = fmaxf(pm, fmaxf(fmaxf(fmaxf(sf[2][0], sf[2][1]), fmaxf(sf[2][2], sf[2][3])),
                             fmaxf(fmaxf(sf[3][0], sf[3][1]), fmaxf(sf[3][2], sf[3][3]))));
        pm = fmaxf(pm, __shfl_xor(pm, 16));
        pm = fmaxf(pm, __shfl_xor(pm, 32));
        float pm2 = pm * c1;
        const bool noresc = __all(pm2 - m2 <= 8.0f);
        float sc = 1.0f;
        if (!noresc) {
            float m2new = fmaxf(m2, pm2);
            sc = exp2f(m2 - m2new);
            m2 = m2new;
        }
        float rsum = 0.f;
#pragma unroll
        for (int kc = 0; kc < 4; ++kc)
#pragma unroll
            for (int r = 0; r < 4; ++r) {
                float p = exp2f(sf[kc][r] * c1 - m2);
                sf[kc][r] = p;
                rsum += p;
            }
        rsum += __shfl_xor(rsum, 16);
        rsum += __shfl_xor(rsum, 32);
        if (noresc) {
            l = l + rsum;
        } else {
            l = l * sc + rsum;
#pragma unroll
            for (int n = 0; n < 8; ++n) {
                f32x4 o = of[n];
                o[0] *= sc; o[1] *= sc; o[2] *= sc; o[3] *= sc;
                of[n] = o;
            }
        }

        // ---- pack P pairs to bf16 dwords ----
        uint32_t cpk[4][2];
#pragma unroll
        for (int kc = 0; kc < 4; ++kc)
#pragma unroll
            for (int hh = 0; hh < 2; ++hh)
                cpk[kc][hh] = cvt_pk_bf16(sf[kc][2 * hh], sf[kc][2 * hh + 1]);

        // ---- O^T += V^T P ----
        __builtin_amdgcn_s_setprio(1);
        {   // kvc = 0
            uint32_t eA0 = __shfl(cpk[0][0], srcA), eA1 = __shfl(cpk[0][1], srcA);
            uint32_t oA0 = __shfl(cpk[1][0], srcA), oA1 = __shfl(cpk[1][1], srcA);
            uint32_t eB0 = __shfl(cpk[0][0], srcB), eB1 = __shfl(cpk[0][1], srcB);
            uint32_t oB0 = __shfl(cpk[1][0], srcB), oB1 = __shfl(cpk[1][1], srcB);
            uint4v pd;
            pd[0] = par ? oA0 : eA0; pd[1] = par ? oA1 : eA1;
            pd[2] = par ? oB0 : eB0; pd[3] = par ? oB1 : eB1;
            short8 pf = __builtin_bit_cast(short8, pd);
            {
                short4v a0 = TR16(vb3, 0),    b0 = TR16(vb3, 1024);
                short4v a1 = TR16(vb3, 128),  b1 = TR16(vb3, 1152);
                short4v a2 = TR16(vb3, 256),  b2 = TR16(vb3, 1280);
                short4v a3 = TR16(vb3, 384),  b3 = TR16(vb3, 1408);
                asm volatile("s_waitcnt lgkmcnt(0)" ::: "memory");
                __builtin_amdgcn_sched_barrier(0);
                of[0] = __builtin_amdgcn_mfma_f32_16x16x32_bf16(CAT8(a0, b0), pf, of[0], 0, 0, 0);
                of[1] = __builtin_amdgcn_mfma_f32_16x16x32_bf16(CAT8(a1, b1), pf, of[1], 0, 0, 0);
                of[2] = __builtin_amdgcn_mfma_f32_16x16x32_bf16(CAT8(a2, b2), pf, of[2], 0, 0, 0);
                of[3] = __builtin_amdgcn_mfma_f32_16x16x32_bf16(CAT8(a3, b3), pf, of[3], 0, 0, 0);
            }
            {
                short4v a0 = TR16(vb3, 512),  b0 = TR16(vb3, 1536);
                short4v a1 = TR16(vb3, 640),  b1 = TR16(vb3, 1664);
                short4v a2 = TR16(vb3, 768),  b2 = TR16(vb3, 1792);
                short4v a3 = TR16(vb3, 896),  b3 = TR16(vb3, 1920);
                asm volatile("s_waitcnt lgkmcnt(0)" ::: "memory");
                __builtin_amdgcn_sched_barrier(0);
                of[4] = __builtin_amdgcn_mfma_f32_16x16x32_bf16(CAT8(a0, b0), pf, of[4], 0, 0, 0);
                of[5] = __builtin_amdgcn_mfma_f32_16x16x32_bf16(CAT8(a1, b1), pf, of[5], 0, 0, 0);
                of[6] = __builtin_amdgcn_mfma_f32_16x16x32_bf16(CAT8(a2, b2), pf, of[6], 0, 0, 0);
                of[7] = __builtin_amdgcn_mfma_f32_16x16x32_bf16(CAT8(a3, b3), pf, of[7], 0, 0, 0);
            }
        }
        {   // kvc = 1
            uint32_t eA0 = __shfl(cpk[2][0], srcA), eA1 = __shfl(cpk[2][1], srcA);
            uint32_t oA0 = __shfl(cpk[3][0], srcA), oA1 = __shfl(cpk[3][1], srcA);
            uint32_t eB0 = __shfl(cpk[2][0], srcB), eB1 = __shfl(cpk[2][1], srcB);
            uint32_t oB0 = __shfl(cpk[3][0], srcB), oB1 = __shfl(cpk[3][1], srcB);
            uint4v pd;
            pd[0] = par ? oA0 : eA0; pd[1] = par ? oA1 : eA1;
            pd[2] = par ? oB0 : eB0; pd[3] = par ? oB1 : eB1;
            short8 pf = __builtin_bit_cast(short8, pd);
            {
                short4v a0 = TR16(vb3, 8192), b0 = TR16(vb3, 9216);
                short4v a1 = TR16(vb3, 8320), b1 = TR16(vb3, 9344);
                short4v a2 = TR16(vb3, 8448), b2 = TR16(vb3, 9472);
                short4v a3 = TR16(vb3, 8576), b3 = TR16(vb3, 9600);
                asm volatile("s_waitcnt lgkmcnt(0)" ::: "memory");
                __builtin_amdgcn_sched_barrier(0);
                of[0] = __builtin_amdgcn_mfma_f32_16x16x32_bf16(CAT8(a0, b0), pf, of[0], 0, 0, 0);
                of[1] = __builtin_amdgcn_mfma_f32_16x16x32_bf16(CAT8(a1, b1), pf, of[1], 0, 0, 0);
                of[2] = __builtin_amdgcn_mfma_f32_16x16x32_bf16(CAT8(a2, b2), pf, of[2], 0, 0, 0);
                of[3] = __builtin_amdgcn_mfma_f32_16x16x32_bf16(CAT8(a3, b3), pf, of[3], 0, 0, 0);
            }
            {
                short4v a0 = TR16(vb3, 8704), b0 = TR16(vb3, 9728);
                short4v a1 = TR16(vb3, 8832), b1 = TR16(vb3, 9856);
                short4v a2 = TR16(vb3, 8960), b2 = TR16(vb3, 9984);
                short4v a3 = TR16(vb3, 9088), b3 = TR16(vb3, 10112);
                asm volatile("s_waitcnt lgkmcnt(0)" ::: "memory");
                __builtin_amdgcn_sched_barrier(0);
                of[4] = __builtin_amdgcn_mfma_f32_16x16x32_bf16(CAT8(a0, b0), pf, of[4], 0, 0, 0);
                of[5] = __builtin_amdgcn_mfma_f32_16x16x32_bf16(CAT8(a1, b1), pf, of[5], 0, 0, 0);
                of[6] = __builtin_amdgcn_mfma_f32_16x16x32_bf16(CAT8(a2, b2), pf, of[6], 0, 0, 0);
                of[7] = __builtin_amdgcn_mfma_f32_16x16x32_bf16(CAT8(a3, b3), pf, of[7], 0, 0, 0);
            }
        }
        __builtin_amdgcn_s_setprio(0);
    }

    // ---- epilogue: lane owns q=qr0+fr; of[n][r] = O[q][dh=n*16+fq*4+r] ----
    float inv = 1.f / l;
    ushort* ob = O + ((size_t)(b * S) + qr0 + fr) * rs + h * 128 + fq * 4;
#pragma unroll
    for (int n = 0; n < 8; ++n) {
        uint2 o2;
        o2.x = cvt_pk_bf16(of[n][0] * inv, of[n][1] * inv);
        o2.y = cvt_pk_bf16(of[n][2] * inv, of[n][3] * inv);
        *reinterpret_cast<uint2*>(ob + n * 16) = o2;
    }
}

// ---------------- launch ----------------
extern "C" void kernel_launch(void* const* d_in, const int* in_sizes, int n_in,
                              void* d_out, int out_size, void* d_ws, size_t ws_size,
                              hipStream_t stream) {
    constexpr int B = 2, S = 2048, HID = 2048, H = 16;
    constexpr int M = B * S;
    const float scale = 0.08838834764831845f;

    const float* x  = (const float*)d_in[0];
    const float* wq = (const float*)d_in[1];
    const float* wk = (const float*)d_in[2];
    const float* wv = (const float*)d_in[3];
    const float* wo = (const float*)d_in[4];
    float* out = (float*)d_out;

    char* ws = (char*)d_ws;
    ushort* xb  = (ushort*)(ws);                    // [4096][2048] bf16; reused as attn out
    ushort* wqb = (ushort*)(ws + 16777216);         // wq,wk,wv casts contiguous (24 MB)
    ushort* qb  = (ushort*)(ws + 41943040);         // q,k,v contiguous (48 MB)
    ushort* kb  = (ushort*)(ws + 58720256);
    ushort* vb  = (ushort*)(ws + 75497472);

    const int XN = M * HID;
    const int WN = HID * HID;

    cast_kernel<<<XN / 4 / 256, 256, 0, stream>>>(x, xb, XN / 4);
    cast3_kernel<<<3 * WN / 4 / 256, 256, 0, stream>>>(wq, wk, wv, wqb, WN / 4);

    // fused QKV projection: one GEMM over concatenated weights -> concatenated q,k,v
    dim3 gq(3 * HID / 128, M / 128);   // (48, 32) = 1536 blocks
    gemm_bt_kernel<ushort><<<gq, 256, 0, stream>>>(xb, wqb, qb, M, HID, HID);

    dim3 ga(S / 128, H, B);            // (16, 16, 2) = 512 blocks x 512 threads
    attn_kernel<<<ga, 512, 0, stream>>>(qb, kb, vb, xb, S, HID, scale);

    cast_kernel<<<WN / 4 / 256, 256, 0, stream>>>(wo, wqb, WN / 4);
    dim3 gg(HID / 128, M / 128);       // (16, 32)
    gemm_bt_kernel<float><<<gg, 256, 0, stream>>>(xb, wqb, out, M, HID, HID);
}

// Round 13
// 326.144 us; speedup vs baseline: 1.2109x; 1.0387x over previous
//
#include <hip/hip_runtime.h>
#include <hip/hip_bf16.h>
#include <stdint.h>

typedef __attribute__((ext_vector_type(8))) short short8;
typedef __attribute__((ext_vector_type(4))) short short4v;
typedef __attribute__((ext_vector_type(4))) float f32x4;
typedef __attribute__((ext_vector_type(4))) unsigned int uint4v;

static __device__ __forceinline__ ushort f2bf(float f) {
    uint32_t u = __builtin_bit_cast(uint32_t, f);
    uint32_t r = (u + 0x7FFFu + ((u >> 16) & 1u)) >> 16;
    return (ushort)r;
}

static __device__ __forceinline__ uint32_t cvt_pk_bf16(float lo, float hi) {
    uint32_t d;
    asm("v_cvt_pk_bf16_f32 %0, %1, %2" : "=v"(d) : "v"(lo), "v"(hi));
    return d;
}

static __device__ __forceinline__ void async_copy16(const void* g, void* l) {
    __builtin_amdgcn_global_load_lds(
        (const __attribute__((address_space(1))) uint32_t*)g,
        (__attribute__((address_space(3))) uint32_t*)l, 16, 0, 0);
}

// ds_read_b64_tr_b16 at base + literal offset. tile = addr & ~127
// ([4][16] bf16 row-major subtile), col = (addr>>3)&15;
// returns 4 bf16 at tile + col*2 + {0,32,64,96}.
#define TR16(P3, IMM)                                                        \
    ({                                                                       \
        short4v _d;                                                          \
        asm volatile("ds_read_b64_tr_b16 %0, %1 offset:" #IMM                \
                     : "=v"(_d) : "v"(P3));                                  \
        _d;                                                                  \
    })

#define CAT8(a, b) __builtin_shufflevector(a, b, 0, 1, 2, 3, 4, 5, 6, 7)

// ---------------- cast fp32 -> bf16 ----------------
__global__ __launch_bounds__(256) void cast_kernel(const float* __restrict__ in,
                                                   ushort* __restrict__ out, int n4) {
    int i = blockIdx.x * 256 + threadIdx.x;
    if (i >= n4) return;
    float4 v = reinterpret_cast<const float4*>(in)[i];
    uint2 o;
    o.x = cvt_pk_bf16(v.x, v.y);
    o.y = cvt_pk_bf16(v.z, v.w);
    reinterpret_cast<uint2*>(out)[i] = o;
}

// cast 3 equal-size fp32 buffers into one contiguous bf16 region
__global__ __launch_bounds__(256) void cast3_kernel(const float* __restrict__ a,
                                                    const float* __restrict__ b,
                                                    const float* __restrict__ c,
                                                    ushort* __restrict__ out, int n4each) {
    int i = blockIdx.x * 256 + threadIdx.x;
    int which = i / n4each;
    int j = i - which * n4each;
    const float* src = which == 0 ? a : (which == 1 ? b : c);
    if (which > 2) return;
    float4 v = reinterpret_cast<const float4*>(src)[j];
    uint2 o;
    o.x = cvt_pk_bf16(v.x, v.y);
    o.y = cvt_pk_bf16(v.z, v.w);
    reinterpret_cast<uint2*>(out)[i] = o;
}

// ---------------- 128-tile GEMM (kept for the final projection) ----------------
static __device__ __forceinline__ void store_val(float* C, size_t idx, float v) { C[idx] = v; }
static __device__ __forceinline__ void store_val(ushort* C, size_t idx, float v) { C[idx] = f2bf(v); }

template <typename OutT>
__global__ __launch_bounds__(256) void gemm_bt_kernel(const ushort* __restrict__ A,
                                                      const ushort* __restrict__ B,
                                                      OutT* __restrict__ C,
                                                      int M, int N, int K) {
    __shared__ __align__(16) ushort As[128 * 32];
    __shared__ __align__(16) ushort Bs[128 * 32];
    const int tid = threadIdx.x;
    const int w = tid >> 6, lane = tid & 63;
    const int fr = lane & 15, fq = lane >> 4;
    const int wr = w >> 1, wc = w & 1;
    const int bpn = N >> 7;
    const int which = blockIdx.x / bpn;
    const int row0 = blockIdx.y * 128;
    const int gcol0 = blockIdx.x * 128;
    const int col0 = gcol0 - which * N;
    OutT* Cw = C + (size_t)which * M * N;

    const int srow = tid >> 2;
    const int scol = (tid & 3) * 8;
    const ushort* ga0 = A + (size_t)(row0 + srow) * K + scol;
    const ushort* ga1 = A + (size_t)(row0 + 64 + srow) * K + scol;
    const ushort* gb0 = B + (size_t)(gcol0 + srow) * K + scol;
    const ushort* gb1 = B + (size_t)(gcol0 + 64 + srow) * K + scol;
    ushort* la0 = &As[(w * 64) * 8];
    ushort* la1 = &As[(256 + w * 64) * 8];
    ushort* lb0 = &Bs[(w * 64) * 8];
    ushort* lb1 = &Bs[(256 + w * 64) * 8];

    f32x4 acc[4][4];
#pragma unroll
    for (int m = 0; m < 4; ++m)
#pragma unroll
        for (int n = 0; n < 4; ++n) acc[m][n] = f32x4{0.f, 0.f, 0.f, 0.f};

    for (int kt = 0; kt < K; kt += 32) {
        __syncthreads();
        async_copy16(ga0 + kt, la0);
        async_copy16(ga1 + kt, la1);
        async_copy16(gb0 + kt, lb0);
        async_copy16(gb1 + kt, lb1);
        __syncthreads();
        short8 af[4], bfr[4];
#pragma unroll
        for (int m = 0; m < 4; ++m)
            af[m] = *(const short8*)&As[(wr * 64 + m * 16 + fr) * 32 + fq * 8];
#pragma unroll
        for (int n = 0; n < 4; ++n)
            bfr[n] = *(const short8*)&Bs[(wc * 64 + n * 16 + fr) * 32 + fq * 8];
#pragma unroll
        for (int m = 0; m < 4; ++m)
#pragma unroll
            for (int n = 0; n < 4; ++n)
                acc[m][n] = __builtin_amdgcn_mfma_f32_16x16x32_bf16(af[m], bfr[n], acc[m][n], 0, 0, 0);
    }

#pragma unroll
    for (int m = 0; m < 4; ++m) {
        const int grow = row0 + wr * 64 + m * 16 + fq * 4;
#pragma unroll
        for (int n = 0; n < 4; ++n) {
            const int gcol = col0 + wc * 64 + n * 16 + fr;
#pragma unroll
            for (int r = 0; r < 4; ++r)
                store_val(Cw, (size_t)(grow + r) * N + gcol, acc[m][n][r]);
        }
    }
}

// ---------------- 256-tile pipelined GEMM (bf16 out) ----------------
// BM=BN=256, BK=64; 8 waves (2M x 4N); per-wave C = 128x64 (8m x 4n frags).
// LDS 128 KiB = {A,B} x 4 regions x 16 KiB; region = K-half (256 rows x 32 cols).
// Region layout: row-pairs in 128B lines, byte = (row>>1)*128 +
//   (((row&1)*64 + colbyte) ^ (((row>>1)&7)<<4)); staged by global_load_lds
// with inverse-swizzled per-lane global source. Pipeline: stage-ahead 3
// K-halves, per-phase s_waitcnt vmcnt(8) + s_barrier (counted, never 0
// mid-loop); tail peels vmcnt(4)/vmcnt(0).
__global__ __launch_bounds__(512, 2) void gemm256_kernel(const ushort* __restrict__ A,
                                                         const ushort* __restrict__ B,
                                                         ushort* __restrict__ C,
                                                         int M, int N, int K) {
    __shared__ __align__(16) char smem[131072];
    const int tid = threadIdx.x, w = tid >> 6, lane = tid & 63;
    const int fr = lane & 15, fq = lane >> 4;
    const int wm = w >> 2, wn = w & 3;
    const int bpn = N >> 8;
    const int which = blockIdx.x / bpn;
    const int row0 = blockIdx.y * 256;
    const int gcol0 = blockIdx.x * 256;
    const int col0 = gcol0 - which * N;
    ushort* Cw = C + (size_t)which * M * N;

    // stage source map for instr p: phys = p*8192 + tid*16; rp = p*64 + (tid>>3);
    // lo = ((tid&7)^((tid>>3)&7))<<4; row = rp*2 + (lo>=64); col = (lo&63)>>1
    const int lo = ((tid & 7) ^ ((tid >> 3) & 7)) << 4;
    const int r0p = ((tid >> 3) << 1) + (lo >> 6);
    const int colE = (lo & 63) >> 1;
    const ushort* Ap0 = A + (size_t)(row0 + r0p) * K + colE;
    const ushort* Ap1 = A + (size_t)(row0 + 128 + r0p) * K + colE;
    const ushort* Bp0 = B + (size_t)(gcol0 + r0p) * K + colE;
    const ushort* Bp1 = B + (size_t)(gcol0 + 128 + r0p) * K + colE;

    char* aregs = smem;
    char* bregs = smem + 65536;
    const int wbyte = w * 1024;

    auto stageH = [&](int h) {
        const int kc = (h >> 1) * 64 + (h & 1) * 32;
        char* ar = aregs + (h & 3) * 16384;
        char* br = bregs + (h & 3) * 16384;
        async_copy16(Ap0 + kc, ar + wbyte);
        async_copy16(Ap1 + kc, ar + 8192 + wbyte);
        async_copy16(Bp0 + kc, br + wbyte);
        async_copy16(Bp1 + kc, br + 8192 + wbyte);
    };

    const int swz = ((fr & 1) * 64 + fq * 16) ^ (((fr >> 1) & 7) << 4);
    const int aBase = (wm * 64 + (fr >> 1)) * 128 + swz;
    const int bBase = (wn * 32 + (fr >> 1)) * 128 + swz;

    f32x4 acc[8][4];
#pragma unroll
    for (int m = 0; m < 8; ++m)
#pragma unroll
        for (int n = 0; n < 4; ++n) acc[m][n] = f32x4{0.f, 0.f, 0.f, 0.f};

    const int nH = K >> 5;   // number of K-halves (64 for K=2048)
    stageH(0); stageH(1); stageH(2);
    asm volatile("s_waitcnt vmcnt(8)\n\ts_barrier" ::: "memory");

    for (int i = 0; i < nH; ++i) {
        if (i + 3 < nH) stageH(i + 3);
        const char* ar = aregs + (i & 3) * 16384 + aBase;
        const char* br = bregs + (i & 3) * 16384 + bBase;
        short8 af[8], bf[4];
#pragma unroll
        for (int m = 0; m < 8; ++m) af[m] = *(const short8*)(ar + m * 1024);
#pragma unroll
        for (int n = 0; n < 4; ++n) bf[n] = *(const short8*)(br + n * 1024);
        __builtin_amdgcn_s_setprio(1);
#pragma unroll
        for (int m = 0; m < 8; ++m)
#pragma unroll
            for (int n = 0; n < 4; ++n)
                acc[m][n] = __builtin_amdgcn_mfma_f32_16x16x32_bf16(af[m], bf[n], acc[m][n], 0, 0, 0);
        __builtin_amdgcn_s_setprio(0);
        if (i < nH - 3)
            asm volatile("s_waitcnt vmcnt(8)\n\ts_barrier" ::: "memory");
        else if (i == nH - 3)
            asm volatile("s_waitcnt vmcnt(4)\n\ts_barrier" ::: "memory");
        else if (i == nH - 2)
            asm volatile("s_waitcnt vmcnt(0)\n\ts_barrier" ::: "memory");
    }

#pragma unroll
    for (int m = 0; m < 8; ++m) {
        const int grow = row0 + wm * 128 + m * 16 + fq * 4;
#pragma unroll
        for (int n = 0; n < 4; ++n) {
            const int gcol = col0 + wn * 64 + n * 16 + fr;
#pragma unroll
            for (int r2 = 0; r2 < 4; ++r2)
                Cw[(size_t)(grow + r2) * N + gcol] = f2bf(acc[m][n][r2]);
        }
    }
}

// ---------------- flash attention fwd (unchanged from R12) ----------------
__global__ __launch_bounds__(512) void attn_kernel(const ushort* __restrict__ Q,
                                                   const ushort* __restrict__ K,
                                                   const ushort* __restrict__ V,
                                                   ushort* __restrict__ O,
                                                   int S, int HID, float scale) {
    __shared__ __align__(16) ushort Ks[64 * 128];   // swz: byte ^= ((row&7)<<4)
    __shared__ __align__(16) ushort Vs[64 * 128];   // [kv/4][dh/16][4][16] subtiled

    const int tid = threadIdx.x, w = tid >> 6, lane = tid & 63;
    const int fr = lane & 15, fq = lane >> 4;
    const int qt = blockIdx.x, h = blockIdx.y, b = blockIdx.z;
    const size_t rs = (size_t)HID;
    const int qr0 = qt * 128 + w * 16;
    const float c1 = scale * 1.4426950408889634f;

    short8 qf[4];
    {
        const ushort* qp = Q + ((size_t)(b * S) + qr0 + fr) * rs + h * 128 + fq * 8;
#pragma unroll
        for (int ks = 0; ks < 4; ++ks) qf[ks] = *(const short8*)(qp + ks * 32);
    }

    f32x4 of[8];
#pragma unroll
    for (int n = 0; n < 8; ++n) of[n] = f32x4{0.f, 0.f, 0.f, 0.f};
    float m2 = -1e30f;
    float l = 0.f;

    const ushort* Kb = K + (size_t)(b * S) * rs + h * 128;
    const ushort* Vb = V + (size_t)(b * S) * rs + h * 128;

    size_t koff[2];
#pragma unroll
    for (int j = 0; j < 2; ++j) {
        int row = j * 32 + w * 4 + (lane >> 4);
        int colb = ((lane & 15) * 16) ^ ((row & 7) << 4);
        koff[j] = (size_t)row * rs + (colb >> 1);
    }
    size_t voff[2];
#pragma unroll
    for (int j = 0; j < 2; ++j) {
        int L = j * 64 + w * 8 + (lane >> 3);
        int kv = (L >> 3) * 4 + ((lane >> 1) & 3);
        int dh = (L & 7) * 16 + (lane & 1) * 8;
        voff[j] = (size_t)kv * rs + dh;
    }

    const __attribute__((address_space(3))) ushort* vb3 =
        (const __attribute__((address_space(3))) ushort*)((const char*)Vs + fq * 2048 + fr * 8);

    const int srcA = fr + 16 * ((2 * fq) & 3);
    const int srcB = fr + 16 * ((2 * fq + 1) & 3);
    const int par = fq >> 1;

    const int nt = S / 64;
    for (int t = 0; t < nt; ++t) {
        __syncthreads();
        const ushort* kt0 = Kb + (size_t)t * 64 * rs;
        const ushort* vt0 = Vb + (size_t)t * 64 * rs;
#pragma unroll
        for (int j = 0; j < 2; ++j)
            async_copy16(kt0 + koff[j], &Ks[j * 4096 + w * 512]);
#pragma unroll
        for (int j = 0; j < 2; ++j)
            async_copy16(vt0 + voff[j], &Vs[j * 4096 + w * 512]);
        __syncthreads();

        f32x4 sf[4];
        __builtin_amdgcn_s_setprio(1);
#pragma unroll
        for (int kc = 0; kc < 4; ++kc) {
            f32x4 s = f32x4{0.f, 0.f, 0.f, 0.f};
#pragma unroll
            for (int ks = 0; ks < 4; ++ks) {
                int row = kc * 16 + fr;
                int pb = (row * 256 + ks * 64 + fq * 16) ^ ((row & 7) << 4);
                short8 kf = *(const short8*)((const char*)Ks + pb);
                s = __builtin_amdgcn_mfma_f32_16x16x32_bf16(kf, qf[ks], s, 0, 0, 0);
            }
            sf[kc] = s;
        }
        __builtin_amdgcn_s_setprio(0);

        float pm = fmaxf(fmaxf(fmaxf(sf[0][0], sf[0][1]), fmaxf(sf[0][2], sf[0][3])),
                         fmaxf(fmaxf(sf[1][0], sf[1][1]), fmaxf(sf[1][2], sf[1][3])));
        pm = fmaxf(pm, fmaxf(fmaxf(fmaxf(sf[2][0], sf[2][1]), fmaxf(sf[2][2], sf[2][3])),
                             fmaxf(fmaxf(sf[3][0], sf[3][1]), fmaxf(sf[3][2], sf[3][3]))));
        pm = fmaxf(pm, __shfl_xor(pm, 16));
        pm = fmaxf(pm, __shfl_xor(pm, 32));
        float pm2 = pm * c1;
        const bool noresc = __all(pm2 - m2 <= 8.0f);
        float sc = 1.0f;
        if (!noresc) {
            float m2new = fmaxf(m2, pm2);
            sc = exp2f(m2 - m2new);
            m2 = m2new;
        }
        float rsum = 0.f;
#pragma unroll
        for (int kc = 0; kc < 4; ++kc)
#pragma unroll
            for (int r = 0; r < 4; ++r) {
                float p = exp2f(sf[kc][r] * c1 - m2);
                sf[kc][r] = p;
                rsum += p;
            }
        rsum += __shfl_xor(rsum, 16);
        rsum += __shfl_xor(rsum, 32);
        if (noresc) {
            l = l + rsum;
        } else {
            l = l * sc + rsum;
#pragma unroll
            for (int n = 0; n < 8; ++n) {
                f32x4 o = of[n];
                o[0] *= sc; o[1] *= sc; o[2] *= sc; o[3] *= sc;
                of[n] = o;
            }
        }

        uint32_t cpk[4][2];
#pragma unroll
        for (int kc = 0; kc < 4; ++kc)
#pragma unroll
            for (int hh = 0; hh < 2; ++hh)
                cpk[kc][hh] = cvt_pk_bf16(sf[kc][2 * hh], sf[kc][2 * hh + 1]);

        __builtin_amdgcn_s_setprio(1);
        {   // kvc = 0
            uint32_t eA0 = __shfl(cpk[0][0], srcA), eA1 = __shfl(cpk[0][1], srcA);
            uint32_t oA0 = __shfl(cpk[1][0], srcA), oA1 = __shfl(cpk[1][1], srcA);
            uint32_t eB0 = __shfl(cpk[0][0], srcB), eB1 = __shfl(cpk[0][1], srcB);
            uint32_t oB0 = __shfl(cpk[1][0], srcB), oB1 = __shfl(cpk[1][1], srcB);
            uint4v pd;
            pd[0] = par ? oA0 : eA0; pd[1] = par ? oA1 : eA1;
            pd[2] = par ? oB0 : eB0; pd[3] = par ? oB1 : eB1;
            short8 pf = __builtin_bit_cast(short8, pd);
            {
                short4v a0 = TR16(vb3, 0),    b0 = TR16(vb3, 1024);
                short4v a1 = TR16(vb3, 128),  b1 = TR16(vb3, 1152);
                short4v a2 = TR16(vb3, 256),  b2 = TR16(vb3, 1280);
                short4v a3 = TR16(vb3, 384),  b3 = TR16(vb3, 1408);
                asm volatile("s_waitcnt lgkmcnt(0)" ::: "memory");
                __builtin_amdgcn_sched_barrier(0);
                of[0] = __builtin_amdgcn_mfma_f32_16x16x32_bf16(CAT8(a0, b0), pf, of[0], 0, 0, 0);
                of[1] = __builtin_amdgcn_mfma_f32_16x16x32_bf16(CAT8(a1, b1), pf, of[1], 0, 0, 0);
                of[2] = __builtin_amdgcn_mfma_f32_16x16x32_bf16(CAT8(a2, b2), pf, of[2], 0, 0, 0);
                of[3] = __builtin_amdgcn_mfma_f32_16x16x32_bf16(CAT8(a3, b3), pf, of[3], 0, 0, 0);
            }
            {
                short4v a0 = TR16(vb3, 512),  b0 = TR16(vb3, 1536);
                short4v a1 = TR16(vb3, 640),  b1 = TR16(vb3, 1664);
                short4v a2 = TR16(vb3, 768),  b2 = TR16(vb3, 1792);
                short4v a3 = TR16(vb3, 896),  b3 = TR16(vb3, 1920);
                asm volatile("s_waitcnt lgkmcnt(0)" ::: "memory");
                __builtin_amdgcn_sched_barrier(0);
                of[4] = __builtin_amdgcn_mfma_f32_16x16x32_bf16(CAT8(a0, b0), pf, of[4], 0, 0, 0);
                of[5] = __builtin_amdgcn_mfma_f32_16x16x32_bf16(CAT8(a1, b1), pf, of[5], 0, 0, 0);
                of[6] = __builtin_amdgcn_mfma_f32_16x16x32_bf16(CAT8(a2, b2), pf, of[6], 0, 0, 0);
                of[7] = __builtin_amdgcn_mfma_f32_16x16x32_bf16(CAT8(a3, b3), pf, of[7], 0, 0, 0);
            }
        }
        {   // kvc = 1
            uint32_t eA0 = __shfl(cpk[2][0], srcA), eA1 = __shfl(cpk[2][1], srcA);
            uint32_t oA0 = __shfl(cpk[3][0], srcA), oA1 = __shfl(cpk[3][1], srcA);
            uint32_t eB0 = __shfl(cpk[2][0], srcB), eB1 = __shfl(cpk[2][1], srcB);
            uint32_t oB0 = __shfl(cpk[3][0], srcB), oB1 = __shfl(cpk[3][1], srcB);
            uint4v pd;
            pd[0] = par ? oA0 : eA0; pd[1] = par ? oA1 : eA1;
            pd[2] = par ? oB0 : eB0; pd[3] = par ? oB1 : eB1;
            short8 pf = __builtin_bit_cast(short8, pd);
            {
                short4v a0 = TR16(vb3, 8192), b0 = TR16(vb3, 9216);
                short4v a1 = TR16(vb3, 8320), b1 = TR16(vb3, 9344);
                short4v a2 = TR16(vb3, 8448), b2 = TR16(vb3, 9472);
                short4v a3 = TR16(vb3, 8576), b3 = TR16(vb3, 9600);
                asm volatile("s_waitcnt lgkmcnt(0)" ::: "memory");
                __builtin_amdgcn_sched_barrier(0);
                of[0] = __builtin_amdgcn_mfma_f32_16x16x32_bf16(CAT8(a0, b0), pf, of[0], 0, 0, 0);
                of[1] = __builtin_amdgcn_mfma_f32_16x16x32_bf16(CAT8(a1, b1), pf, of[1], 0, 0, 0);
                of[2] = __builtin_amdgcn_mfma_f32_16x16x32_bf16(CAT8(a2, b2), pf, of[2], 0, 0, 0);
                of[3] = __builtin_amdgcn_mfma_f32_16x16x32_bf16(CAT8(a3, b3), pf, of[3], 0, 0, 0);
            }
            {
                short4v a0 = TR16(vb3, 8704), b0 = TR16(vb3, 9728);
                short4v a1 = TR16(vb3, 8832), b1 = TR16(vb3, 9856);
                short4v a2 = TR16(vb3, 8960), b2 = TR16(vb3, 9984);
                short4v a3 = TR16(vb3, 9088), b3 = TR16(vb3, 10112);
                asm volatile("s_waitcnt lgkmcnt(0)" ::: "memory");
                __builtin_amdgcn_sched_barrier(0);
                of[4] = __builtin_amdgcn_mfma_f32_16x16x32_bf16(CAT8(a0, b0), pf, of[4], 0, 0, 0);
                of[5] = __builtin_amdgcn_mfma_f32_16x16x32_bf16(CAT8(a1, b1), pf, of[5], 0, 0, 0);
                of[6] = __builtin_amdgcn_mfma_f32_16x16x32_bf16(CAT8(a2, b2), pf, of[6], 0, 0, 0);
                of[7] = __builtin_amdgcn_mfma_f32_16x16x32_bf16(CAT8(a3, b3), pf, of[7], 0, 0, 0);
            }
        }
        __builtin_amdgcn_s_setprio(0);
    }

    float inv = 1.f / l;
    ushort* ob = O + ((size_t)(b * S) + qr0 + fr) * rs + h * 128 + fq * 4;
#pragma unroll
    for (int n = 0; n < 8; ++n) {
        uint2 o2;
        o2.x = cvt_pk_bf16(of[n][0] * inv, of[n][1] * inv);
        o2.y = cvt_pk_bf16(of[n][2] * inv, of[n][3] * inv);
        *reinterpret_cast<uint2*>(ob + n * 16) = o2;
    }
}

// ---------------- launch ----------------
extern "C" void kernel_launch(void* const* d_in, const int* in_sizes, int n_in,
                              void* d_out, int out_size, void* d_ws, size_t ws_size,
                              hipStream_t stream) {
    constexpr int B = 2, S = 2048, HID = 2048, H = 16;
    constexpr int M = B * S;
    const float scale = 0.08838834764831845f;

    const float* x  = (const float*)d_in[0];
    const float* wq = (const float*)d_in[1];
    const float* wk = (const float*)d_in[2];
    const float* wv = (const float*)d_in[3];
    const float* wo = (const float*)d_in[4];
    float* out = (float*)d_out;

    char* ws = (char*)d_ws;
    ushort* xb  = (ushort*)(ws);                    // [4096][2048] bf16; reused as attn out
    ushort* wqb = (ushort*)(ws + 16777216);         // wq,wk,wv casts contiguous (24 MB)
    ushort* qb  = (ushort*)(ws + 41943040);         // q,k,v contiguous (48 MB)
    ushort* kb  = (ushort*)(ws + 58720256);
    ushort* vb  = (ushort*)(ws + 75497472);

    const int XN = M * HID;
    const int WN = HID * HID;

    cast_kernel<<<XN / 4 / 256, 256, 0, stream>>>(x, xb, XN / 4);
    cast3_kernel<<<3 * WN / 4 / 256, 256, 0, stream>>>(wq, wk, wv, wqb, WN / 4);

    // fused QKV projection: 256-tile pipelined GEMM over concatenated weights
    dim3 gq(3 * HID / 256, M / 256);   // (24, 16) = 384 blocks x 512 threads
    gemm256_kernel<<<gq, 512, 0, stream>>>(xb, wqb, qb, M, HID, HID);

    dim3 ga(S / 128, H, B);            // (16, 16, 2) = 512 blocks x 512 threads
    attn_kernel<<<ga, 512, 0, stream>>>(qb, kb, vb, xb, S, HID, scale);

    cast_kernel<<<WN / 4 / 256, 256, 0, stream>>>(wo, wqb, WN / 4);
    dim3 gg(HID / 128, M / 128);       // (16, 32)
    gemm_bt_kernel<float><<<gg, 256, 0, stream>>>(xb, wqb, out, M, HID, HID);
}

// Round 14
// 322.742 us; speedup vs baseline: 1.2237x; 1.0105x over previous
//
#include <hip/hip_runtime.h>
#include <hip/hip_bf16.h>
#include <stdint.h>

typedef __attribute__((ext_vector_type(8))) short short8;
typedef __attribute__((ext_vector_type(4))) float f32x4;
typedef __attribute__((ext_vector_type(4))) unsigned int uint4v;

static __device__ __forceinline__ ushort f2bf(float f) {
    uint32_t u = __builtin_bit_cast(uint32_t, f);
    uint32_t r = (u + 0x7FFFu + ((u >> 16) & 1u)) >> 16;
    return (ushort)r;
}

static __device__ __forceinline__ uint32_t cvt_pk_bf16(float lo, float hi) {
    uint32_t d;
    asm("v_cvt_pk_bf16_f32 %0, %1, %2" : "=v"(d) : "v"(lo), "v"(hi));
    return d;
}

static __device__ __forceinline__ void async_copy16(const void* g, void* l) {
    __builtin_amdgcn_global_load_lds(
        (const __attribute__((address_space(1))) uint32_t*)g,
        (__attribute__((address_space(3))) uint32_t*)l, 16, 0, 0);
}

// ---------------- cast fp32 -> bf16 ----------------
__global__ __launch_bounds__(256) void cast_kernel(const float* __restrict__ in,
                                                   ushort* __restrict__ out, int n4) {
    int i = blockIdx.x * 256 + threadIdx.x;
    if (i >= n4) return;
    float4 v = reinterpret_cast<const float4*>(in)[i];
    uint2 o;
    o.x = cvt_pk_bf16(v.x, v.y);
    o.y = cvt_pk_bf16(v.z, v.w);
    reinterpret_cast<uint2*>(out)[i] = o;
}

// cast 3 equal-size fp32 buffers into one contiguous bf16 region
__global__ __launch_bounds__(256) void cast3_kernel(const float* __restrict__ a,
                                                    const float* __restrict__ b,
                                                    const float* __restrict__ c,
                                                    ushort* __restrict__ out, int n4each) {
    int i = blockIdx.x * 256 + threadIdx.x;
    int which = i / n4each;
    int j = i - which * n4each;
    const float* src = which == 0 ? a : (which == 1 ? b : c);
    if (which > 2) return;
    float4 v = reinterpret_cast<const float4*>(src)[j];
    uint2 o;
    o.x = cvt_pk_bf16(v.x, v.y);
    o.y = cvt_pk_bf16(v.z, v.w);
    reinterpret_cast<uint2*>(out)[i] = o;
}

// ---------------- 128-tile GEMM ----------------
static __device__ __forceinline__ void store_val(float* C, size_t idx, float v) { C[idx] = v; }
static __device__ __forceinline__ void store_val(ushort* C, size_t idx, float v) { C[idx] = f2bf(v); }

template <typename OutT>
__global__ __launch_bounds__(256) void gemm_bt_kernel(const ushort* __restrict__ A,
                                                      const ushort* __restrict__ B,
                                                      OutT* __restrict__ C,
                                                      int M, int N, int K) {
    __shared__ __align__(16) ushort As[128 * 32];
    __shared__ __align__(16) ushort Bs[128 * 32];
    const int tid = threadIdx.x;
    const int w = tid >> 6, lane = tid & 63;
    const int fr = lane & 15, fq = lane >> 4;
    const int wr = w >> 1, wc = w & 1;
    const int bpn = N >> 7;
    const int which = blockIdx.x / bpn;
    const int row0 = blockIdx.y * 128;
    const int gcol0 = blockIdx.x * 128;
    const int col0 = gcol0 - which * N;
    OutT* Cw = C + (size_t)which * M * N;

    const int srow = tid >> 2;
    const int scol = (tid & 3) * 8;
    const ushort* ga0 = A + (size_t)(row0 + srow) * K + scol;
    const ushort* ga1 = A + (size_t)(row0 + 64 + srow) * K + scol;
    const ushort* gb0 = B + (size_t)(gcol0 + srow) * K + scol;
    const ushort* gb1 = B + (size_t)(gcol0 + 64 + srow) * K + scol;
    ushort* la0 = &As[(w * 64) * 8];
    ushort* la1 = &As[(256 + w * 64) * 8];
    ushort* lb0 = &Bs[(w * 64) * 8];
    ushort* lb1 = &Bs[(256 + w * 64) * 8];

    f32x4 acc[4][4];
#pragma unroll
    for (int m = 0; m < 4; ++m)
#pragma unroll
        for (int n = 0; n < 4; ++n) acc[m][n] = f32x4{0.f, 0.f, 0.f, 0.f};

    for (int kt = 0; kt < K; kt += 32) {
        __syncthreads();
        async_copy16(ga0 + kt, la0);
        async_copy16(ga1 + kt, la1);
        async_copy16(gb0 + kt, lb0);
        async_copy16(gb1 + kt, lb1);
        __syncthreads();
        short8 af[4], bfr[4];
#pragma unroll
        for (int m = 0; m < 4; ++m)
            af[m] = *(const short8*)&As[(wr * 64 + m * 16 + fr) * 32 + fq * 8];
#pragma unroll
        for (int n = 0; n < 4; ++n)
            bfr[n] = *(const short8*)&Bs[(wc * 64 + n * 16 + fr) * 32 + fq * 8];
#pragma unroll
        for (int m = 0; m < 4; ++m)
#pragma unroll
            for (int n = 0; n < 4; ++n)
                acc[m][n] = __builtin_amdgcn_mfma_f32_16x16x32_bf16(af[m], bfr[n], acc[m][n], 0, 0, 0);
    }

#pragma unroll
    for (int m = 0; m < 4; ++m) {
        const int grow = row0 + wr * 64 + m * 16 + fq * 4;
#pragma unroll
        for (int n = 0; n < 4; ++n) {
            const int gcol = col0 + wc * 64 + n * 16 + fr;
#pragma unroll
            for (int r = 0; r < 4; ++r)
                store_val(Cw, (size_t)(grow + r) * N + gcol, acc[m][n][r]);
        }
    }
}

// ---------------- 256-tile pipelined GEMM (bf16 out) ----------------
__global__ __launch_bounds__(512, 2) void gemm256_kernel(const ushort* __restrict__ A,
                                                         const ushort* __restrict__ B,
                                                         ushort* __restrict__ C,
                                                         int M, int N, int K) {
    __shared__ __align__(16) char smem[131072];
    const int tid = threadIdx.x, w = tid >> 6, lane = tid & 63;
    const int fr = lane & 15, fq = lane >> 4;
    const int wm = w >> 2, wn = w & 3;
    const int bpn = N >> 8;
    const int which = blockIdx.x / bpn;
    const int row0 = blockIdx.y * 256;
    const int gcol0 = blockIdx.x * 256;
    const int col0 = gcol0 - which * N;
    ushort* Cw = C + (size_t)which * M * N;

    const int lo = ((tid & 7) ^ ((tid >> 3) & 7)) << 4;
    const int r0p = ((tid >> 3) << 1) + (lo >> 6);
    const int colE = (lo & 63) >> 1;
    const ushort* Ap0 = A + (size_t)(row0 + r0p) * K + colE;
    const ushort* Ap1 = A + (size_t)(row0 + 128 + r0p) * K + colE;
    const ushort* Bp0 = B + (size_t)(gcol0 + r0p) * K + colE;
    const ushort* Bp1 = B + (size_t)(gcol0 + 128 + r0p) * K + colE;

    char* aregs = smem;
    char* bregs = smem + 65536;
    const int wbyte = w * 1024;

    auto stageH = [&](int h) {
        const int kc = (h >> 1) * 64 + (h & 1) * 32;
        char* ar = aregs + (h & 3) * 16384;
        char* br = bregs + (h & 3) * 16384;
        async_copy16(Ap0 + kc, ar + wbyte);
        async_copy16(Ap1 + kc, ar + 8192 + wbyte);
        async_copy16(Bp0 + kc, br + wbyte);
        async_copy16(Bp1 + kc, br + 8192 + wbyte);
    };

    const int swz = ((fr & 1) * 64 + fq * 16) ^ (((fr >> 1) & 7) << 4);
    const int aBase = (wm * 64 + (fr >> 1)) * 128 + swz;
    const int bBase = (wn * 32 + (fr >> 1)) * 128 + swz;

    f32x4 acc[8][4];
#pragma unroll
    for (int m = 0; m < 8; ++m)
#pragma unroll
        for (int n = 0; n < 4; ++n) acc[m][n] = f32x4{0.f, 0.f, 0.f, 0.f};

    const int nH = K >> 5;
    stageH(0); stageH(1); stageH(2);
    asm volatile("s_waitcnt vmcnt(8)\n\ts_barrier" ::: "memory");

    for (int i = 0; i < nH; ++i) {
        if (i + 3 < nH) stageH(i + 3);
        const char* ar = aregs + (i & 3) * 16384 + aBase;
        const char* br = bregs + (i & 3) * 16384 + bBase;
        short8 af[8], bf[4];
#pragma unroll
        for (int m = 0; m < 8; ++m) af[m] = *(const short8*)(ar + m * 1024);
#pragma unroll
        for (int n = 0; n < 4; ++n) bf[n] = *(const short8*)(br + n * 1024);
        __builtin_amdgcn_s_setprio(1);
#pragma unroll
        for (int m = 0; m < 8; ++m)
#pragma unroll
            for (int n = 0; n < 4; ++n)
                acc[m][n] = __builtin_amdgcn_mfma_f32_16x16x32_bf16(af[m], bf[n], acc[m][n], 0, 0, 0);
        __builtin_amdgcn_s_setprio(0);
        if (i < nH - 3)
            asm volatile("s_waitcnt vmcnt(8)\n\ts_barrier" ::: "memory");
        else if (i == nH - 3)
            asm volatile("s_waitcnt vmcnt(4)\n\ts_barrier" ::: "memory");
        else if (i == nH - 2)
            asm volatile("s_waitcnt vmcnt(0)\n\ts_barrier" ::: "memory");
    }

#pragma unroll
    for (int m = 0; m < 8; ++m) {
        const int grow = row0 + wm * 128 + m * 16 + fq * 4;
#pragma unroll
        for (int n = 0; n < 4; ++n) {
            const int gcol = col0 + wn * 64 + n * 16 + fr;
#pragma unroll
            for (int r2 = 0; r2 < 4; ++r2)
                Cw[(size_t)(grow + r2) * N + gcol] = f2bf(acc[m][n][r2]);
        }
    }
}

// ---------------- flash attention fwd ----------------
// 8 waves x 16 q-rows = QBLK 128; KBLK=64; LDS 32 KiB (Ks 16K + Vts 16K).
// V consumed from pre-transposed VT[dh_global][b*S+s] (row stride 2S):
// Vts[128 dh][64 kv] staged like K (linear LDS dest, pre-swizzled source);
// PV A-frag = plain b128 read -> no tr16, no 4-way conflicts.
// Grid: x = b*16+h (XCD-clusters all q-tiles of one head), y = qt.
__global__ __launch_bounds__(512) void attn_kernel(const ushort* __restrict__ Q,
                                                   const ushort* __restrict__ K,
                                                   const ushort* __restrict__ VT,
                                                   ushort* __restrict__ O,
                                                   int S, int HID, float scale) {
    __shared__ __align__(16) ushort Ks[64 * 128];    // swz: byte ^= ((row&7)<<4)
    __shared__ __align__(16) ushort Vts[128 * 64];   // [dh][kv], swz: byte ^= ((row&7)<<4)

    const int tid = threadIdx.x, w = tid >> 6, lane = tid & 63;
    const int fr = lane & 15, fq = lane >> 4;
    const int h = blockIdx.x & 15, b = blockIdx.x >> 4, qt = blockIdx.y;
    const size_t rs = (size_t)HID;
    const size_t vs = (size_t)(2 * S);   // VT row stride
    const int qr0 = qt * 128 + w * 16;
    const float c1 = scale * 1.4426950408889634f;

    short8 qf[4];
    {
        const ushort* qp = Q + ((size_t)(b * S) + qr0 + fr) * rs + h * 128 + fq * 8;
#pragma unroll
        for (int ks = 0; ks < 4; ++ks) qf[ks] = *(const short8*)(qp + ks * 32);
    }

    f32x4 of[8];
#pragma unroll
    for (int n = 0; n < 8; ++n) of[n] = f32x4{0.f, 0.f, 0.f, 0.f};
    float m2 = -1e30f;
    float l = 0.f;

    const ushort* Kb = K + (size_t)(b * S) * rs + h * 128;
    const ushort* Vb = VT + (size_t)(h * 128) * vs + b * S;

    // K staging (2 gloads): rows j*32 + w*4 + (lane>>4)
    size_t koff[2];
#pragma unroll
    for (int j = 0; j < 2; ++j) {
        int row = j * 32 + w * 4 + (lane >> 4);
        int colb = ((lane & 15) * 16) ^ ((row & 7) << 4);
        koff[j] = (size_t)row * rs + (colb >> 1);
    }
    // VT staging (2 gloads): LDS byte A=j*8192+tid*16 -> row=j*64+(tid>>3)
    size_t vtoff[2];
#pragma unroll
    for (int j = 0; j < 2; ++j) {
        int row = j * 64 + (tid >> 3);
        int colb = ((tid & 7) * 16) ^ ((row & 7) << 4);
        vtoff[j] = (size_t)row * vs + (colb >> 1);
    }

    const int srcA = fr + 16 * ((2 * fq) & 3);
    const int srcB = fr + 16 * ((2 * fq + 1) & 3);
    const int par = fq >> 1;

    const int nt = S / 64;
    for (int t = 0; t < nt; ++t) {
        __syncthreads();
        const ushort* kt0 = Kb + (size_t)t * 64 * rs;
        const ushort* vt0 = Vb + (size_t)t * 64;
#pragma unroll
        for (int j = 0; j < 2; ++j)
            async_copy16(kt0 + koff[j], &Ks[j * 4096 + w * 512]);
#pragma unroll
        for (int j = 0; j < 2; ++j)
            async_copy16(vt0 + vtoff[j], &Vts[j * 4096 + w * 512]);
        __syncthreads();

        // ---- S^T = K Q^T : lane holds S[kv=kc*16+fq*4+r][q=fr] ----
        f32x4 sf[4];
        __builtin_amdgcn_s_setprio(1);
#pragma unroll
        for (int kc = 0; kc < 4; ++kc) {
            f32x4 s = f32x4{0.f, 0.f, 0.f, 0.f};
#pragma unroll
            for (int ks = 0; ks < 4; ++ks) {
                int row = kc * 16 + fr;
                int pb = (row * 256 + ks * 64 + fq * 16) ^ ((row & 7) << 4);
                short8 kf = *(const short8*)((const char*)Ks + pb);
                s = __builtin_amdgcn_mfma_f32_16x16x32_bf16(kf, qf[ks], s, 0, 0, 0);
            }
            sf[kc] = s;
        }
        __builtin_amdgcn_s_setprio(0);

        // ---- online softmax, lane-local (q = fr), defer-max THR=8 ----
        float pm = fmaxf(fmaxf(fmaxf(sf[0][0], sf[0][1]), fmaxf(sf[0][2], sf[0][3])),
                         fmaxf(fmaxf(sf[1][0], sf[1][1]), fmaxf(sf[1][2], sf[1][3])));
        pm = fmaxf(pm, fmaxf(fmaxf(fmaxf(sf[2][0], sf[2][1]), fmaxf(sf[2][2], sf[2][3])),
                             fmaxf(fmaxf(sf[3][0], sf[3][1]), fmaxf(sf[3][2], sf[3][3]))));
        pm = fmaxf(pm, __shfl_xor(pm, 16));
        pm = fmaxf(pm, __shfl_xor(pm, 32));
        float pm2 = pm * c1;
        const bool noresc = __all(pm2 - m2 <= 8.0f);
        float sc = 1.0f;
        if (!noresc) {
            float m2new = fmaxf(m2, pm2);
            sc = exp2f(m2 - m2new);
            m2 = m2new;
        }
        float rsum = 0.f;
#pragma unroll
        for (int kc = 0; kc < 4; ++kc)
#pragma unroll
            for (int r = 0; r < 4; ++r) {
                float p = exp2f(sf[kc][r] * c1 - m2);
                sf[kc][r] = p;
                rsum += p;
            }
        rsum += __shfl_xor(rsum, 16);
        rsum += __shfl_xor(rsum, 32);
        if (noresc) {
            l = l + rsum;
        } else {
            l = l * sc + rsum;
#pragma unroll
            for (int n = 0; n < 8; ++n) {
                f32x4 o = of[n];
                o[0] *= sc; o[1] *= sc; o[2] *= sc; o[3] *= sc;
                of[n] = o;
            }
        }

        // ---- pack P pairs to bf16 dwords ----
        uint32_t cpk[4][2];
#pragma unroll
        for (int kc = 0; kc < 4; ++kc)
#pragma unroll
            for (int hh = 0; hh < 2; ++hh)
                cpk[kc][hh] = cvt_pk_bf16(sf[kc][2 * hh], sf[kc][2 * hh + 1]);

        // ---- O^T += V^T P : vf = plain b128 reads of Vts ----
        __builtin_amdgcn_s_setprio(1);
#pragma unroll
        for (int kvc = 0; kvc < 2; ++kvc) {
            uint32_t eA0 = __shfl(cpk[2 * kvc][0], srcA), eA1 = __shfl(cpk[2 * kvc][1], srcA);
            uint32_t oA0 = __shfl(cpk[2 * kvc + 1][0], srcA), oA1 = __shfl(cpk[2 * kvc + 1][1], srcA);
            uint32_t eB0 = __shfl(cpk[2 * kvc][0], srcB), eB1 = __shfl(cpk[2 * kvc][1], srcB);
            uint32_t oB0 = __shfl(cpk[2 * kvc + 1][0], srcB), oB1 = __shfl(cpk[2 * kvc + 1][1], srcB);
            uint4v pd;
            pd[0] = par ? oA0 : eA0; pd[1] = par ? oA1 : eA1;
            pd[2] = par ? oB0 : eB0; pd[3] = par ? oB1 : eB1;
            short8 pf = __builtin_bit_cast(short8, pd);
#pragma unroll
            for (int n = 0; n < 8; ++n) {
                int row = n * 16 + fr;
                int pb = row * 128 + ((kvc * 64 + fq * 16) ^ ((row & 7) << 4));
                short8 vf = *(const short8*)((const char*)Vts + pb);
                of[n] = __builtin_amdgcn_mfma_f32_16x16x32_bf16(vf, pf, of[n], 0, 0, 0);
            }
        }
        __builtin_amdgcn_s_setprio(0);
    }

    // ---- epilogue: lane owns q=qr0+fr; of[n][r] = O[q][dh=n*16+fq*4+r] ----
    float inv = 1.f / l;
    ushort* ob = O + ((size_t)(b * S) + qr0 + fr) * rs + h * 128 + fq * 4;
#pragma unroll
    for (int n = 0; n < 8; ++n) {
        uint2 o2;
        o2.x = cvt_pk_bf16(of[n][0] * inv, of[n][1] * inv);
        o2.y = cvt_pk_bf16(of[n][2] * inv, of[n][3] * inv);
        *reinterpret_cast<uint2*>(ob + n * 16) = o2;
    }
}

// ---------------- launch ----------------
extern "C" void kernel_launch(void* const* d_in, const int* in_sizes, int n_in,
                              void* d_out, int out_size, void* d_ws, size_t ws_size,
                              hipStream_t stream) {
    constexpr int B = 2, S = 2048, HID = 2048, H = 16;
    constexpr int M = B * S;
    const float scale = 0.08838834764831845f;

    const float* x  = (const float*)d_in[0];
    const float* wq = (const float*)d_in[1];
    const float* wk = (const float*)d_in[2];
    const float* wv = (const float*)d_in[3];
    const float* wo = (const float*)d_in[4];
    float* out = (float*)d_out;

    char* ws = (char*)d_ws;
    ushort* xb  = (ushort*)(ws);                    // [4096][2048] bf16; reused as attn out
    ushort* wqb = (ushort*)(ws + 16777216);         // wq,wk,wv casts contiguous (24 MB)
    ushort* wvb = (ushort*)(ws + 33554432);
    ushort* qb  = (ushort*)(ws + 41943040);         // q,k contiguous (32 MB)
    ushort* kb  = (ushort*)(ws + 58720256);
    ushort* vtb = (ushort*)(ws + 75497472);         // V^T [2048][4096] (16 MB)

    const int XN = M * HID;
    const int WN = HID * HID;

    cast_kernel<<<XN / 4 / 256, 256, 0, stream>>>(x, xb, XN / 4);
    cast3_kernel<<<3 * WN / 4 / 256, 256, 0, stream>>>(wq, wk, wv, wqb, WN / 4);

    // Q,K projection: 256-tile pipelined GEMM over concatenated wq,wk
    dim3 gq(2 * HID / 256, M / 256);   // (16, 16) = 256 blocks x 512 threads
    gemm256_kernel<<<gq, 512, 0, stream>>>(xb, wqb, qb, M, HID, HID);

    // V^T projection: V^T[i][j] = sum_k wv[i][k] x[j][k]
    dim3 gv(M / 128, HID / 128);       // (32, 16) = 512 blocks
    gemm_bt_kernel<ushort><<<gv, 256, 0, stream>>>(wvb, xb, vtb, HID, M, HID);

    dim3 ga(H * B, S / 128);           // (32, 16): x=(b,h) clusters on XCDs
    attn_kernel<<<ga, 512, 0, stream>>>(qb, kb, vtb, xb, S, HID, scale);

    cast_kernel<<<WN / 4 / 256, 256, 0, stream>>>(wo, wqb, WN / 4);
    dim3 gg(HID / 128, M / 128);       // (16, 32)
    gemm_bt_kernel<float><<<gg, 256, 0, stream>>>(xb, wqb, out, M, HID, HID);
}